// Round 10
// baseline (1658.450 us; speedup 1.0000x reference)
//
#include <hip/hip_runtime.h>
#include <cstdint>
#include <cstddef>

#define T_SEQ 4096
#define HID 3072
#define NH 16
#define DKH 128
#define KD 2048
#define VD 2048
#define N_QKVZ 8192
#define CONV_CH 6144
#define MROWS 8192  // B*T

typedef unsigned short u16;
typedef unsigned int u32;

typedef __attribute__((ext_vector_type(8))) short bf16x8;
typedef __attribute__((ext_vector_type(4))) float f32x4;

__device__ __forceinline__ float bf2f(u16 u){ u32 t=((u32)u)<<16; float f; __builtin_memcpy(&f,&t,4); return f; }
__device__ __forceinline__ float bflo(u32 u){ u32 t=u<<16; float f; __builtin_memcpy(&f,&t,4); return f; }
__device__ __forceinline__ float bfhi(u32 u){ u32 t=u&0xffff0000u; float f; __builtin_memcpy(&f,&t,4); return f; }
__device__ __forceinline__ u16 f2bf(float f){ u32 i; __builtin_memcpy(&i,&f,4); return (u16)((i + 0x7fffu + ((i>>16)&1u))>>16); }

__device__ __forceinline__ void gl_lds16(const u16* g, u16* l){
    __builtin_amdgcn_global_load_lds(
        (const __attribute__((address_space(1))) void*)g,
        (__attribute__((address_space(3))) void*)l, 16, 0, 0);
}

__device__ __forceinline__ bf16x8 frag(const u16* p, int row, int stride, int k0){
    return *(const bf16x8*)(p + (size_t)row*stride + k0);
}

// ---------- cast f32 -> bf16 (flat) ----------
__global__ void k_cast(const float* __restrict__ in, u16* __restrict__ out, int n4){
    int stride = gridDim.x*blockDim.x;
    for (int i = blockIdx.x*blockDim.x + threadIdx.x; i < n4; i += stride){
        float4 v = ((const float4*)in)[i];
        u32 lo = (u32)f2bf(v.x) | ((u32)f2bf(v.y)<<16);
        u32 hi = (u32)f2bf(v.z) | ((u32)f2bf(v.w)<<16);
        ((uint2*)out)[i] = make_uint2(lo,hi);
    }
}

// ---------- transpose + cast: in[R][C] f32 -> out[C][R] bf16 ----------
__global__ void k_transpose_cast(const float* __restrict__ in, u16* __restrict__ out, int R, int C){
    __shared__ u16 tile[32][33];
    int nbc = C >> 5;
    int bc = blockIdx.x % nbc, br = blockIdx.x / nbc;
    int c0 = bc<<5, r0 = br<<5;
    int tx = threadIdx.x & 31, ty = threadIdx.x >> 5;
    #pragma unroll
    for (int i=0;i<4;i++){
        int r = ty + i*8;
        tile[r][tx] = f2bf(in[(size_t)(r0+r)*C + c0 + tx]);
    }
    __syncthreads();
    #pragma unroll
    for (int i=0;i<4;i++){
        int r = ty + i*8;
        out[(size_t)(c0+r)*R + r0 + tx] = tile[tx][r];
    }
}

// ======== 256x128-tile GEMM, BK=64, 8 waves, 3-slot LDS pipeline (depth-2 counted vmcnt) ========
// C = A[M][K] * Bt[N][K]^T, column-split output (split at multiple of 128).
template<bool OUT_BF16>
__global__ __launch_bounds__(512, 2) void k_gemm3(const u16* __restrict__ A, const u16* __restrict__ Bt,
                                                 void* __restrict__ C1, void* __restrict__ C2,
                                                 int M, int N, int K, int csplit, int ld1, int ld2){
    __shared__ __align__(16) u16 AsB[3*256*64];   // 96 KB: 3 A-slots
    __shared__ __align__(16) u16 BsB[3*128*64];   // 48 KB: 3 B-slots
    const int tid  = threadIdx.x;
    const int lane = tid & 63;
    const int wave = tid >> 6;
    const int wm = wave >> 1;            // 0..3 : 64-row slice
    const int wn = wave & 1;             // 0..1 : 64-col slice
    const int lr = lane & 15, lg = lane >> 4;
    // grouped ordering: supertiles of 8 bm rows (M/256 = 32, % 8 == 0)
    const int nbn = N >> 7;
    const int per = 8*nbn;
    const int grp = blockIdx.x / per, rem = blockIdx.x % per;
    const int bm = grp*8 + (rem & 7);
    const int bn = rem >> 3;
    f32x4 acc[4][4] = {};
    const size_t aRow0 = (size_t)bm*256;
    const size_t bRow0 = (size_t)bn*128;
    const int srow = tid >> 3;           // 0..63
    const int scol = (tid & 7) * 8;

    auto STAGE = [&](int t, int slot){   // 6 loads: A 4x16KB-chunks? (4x64rows), B 2x64rows
        const u16* ga = A  + (aRow0 + srow)*K + t*64 + scol;
        const u16* gb = Bt + (bRow0 + srow)*K + t*64 + scol;
        u16* la = AsB + slot*(256*64) + tid*8;
        u16* lb = BsB + slot*(128*64) + tid*8;
        #pragma unroll
        for (int j=0;j<4;j++) gl_lds16(ga + (size_t)(j*64)*K, la + j*4096);
        #pragma unroll
        for (int j=0;j<2;j++) gl_lds16(gb + (size_t)(j*64)*K, lb + j*4096);
    };

    const int NT = K >> 6;
    STAGE(0, 0);
    if (NT > 1) STAGE(1, 1);

    for (int t=0; t<NT; t++){
        const int slot = t % 3;
        if (t+2 < NT){
            STAGE(t+2, (t+2)%3);                       // slot(t+2)==slot(t-1): freed at end of iter t-1
            asm volatile("s_waitcnt vmcnt(12)" ::: "memory");   // tile t landed; t+1,t+2 in flight
        } else if (t+1 < NT){
            asm volatile("s_waitcnt vmcnt(6)" ::: "memory");
        } else {
            asm volatile("s_waitcnt vmcnt(0)" ::: "memory");
        }
        __builtin_amdgcn_sched_barrier(0);
        __builtin_amdgcn_s_barrier();                  // all waves: tile t visible
        __builtin_amdgcn_sched_barrier(0);
        const u16* Asl = AsB + slot*(256*64);
        const u16* Bsl = BsB + slot*(128*64);
        #pragma unroll
        for (int kk=0; kk<2; kk++){
            bf16x8 af[4], bfv[4];
            #pragma unroll
            for (int i=0;i<4;i++){
                af[i]  = frag(Asl, wm*64 + i*16 + lr, 64, kk*32 + lg*8);
                bfv[i] = frag(Bsl, wn*64 + i*16 + lr, 64, kk*32 + lg*8);
            }
            __builtin_amdgcn_s_setprio(1);
            #pragma unroll
            for (int i=0;i<4;i++)
                #pragma unroll
                for (int j=0;j<4;j++)
                    acc[i][j] = __builtin_amdgcn_mfma_f32_16x16x32_bf16(af[i], bfv[j], acc[i][j], 0, 0, 0);
            __builtin_amdgcn_s_setprio(0);
        }
        asm volatile("s_waitcnt lgkmcnt(0)" ::: "memory");   // my ds_reads of slot retired (vmcnt NOT drained)
        __builtin_amdgcn_sched_barrier(0);
        __builtin_amdgcn_s_barrier();                        // slot(t) free for staging at iter t+1
        __builtin_amdgcn_sched_barrier(0);
    }

    if (OUT_BF16){
        // LDS-bounce epilogue (slots dead): 256x136 bf16 tile, vector stores
        u16* Cs = AsB;                   // 256*136*2 = 69632 B <= 96 KB
        #pragma unroll
        for (int i=0;i<4;i++)
            #pragma unroll
            for (int j=0;j<4;j++)
                #pragma unroll
                for (int r=0;r<4;r++)
                    Cs[(wm*64 + i*16 + lg*4 + r)*136 + wn*64 + j*16 + lr] = f2bf(acc[i][j][r]);
        __syncthreads();
        int row = tid >> 1, half = tid & 1;
        int colbase = bn*128 + half*64;
        u16* dst; int ld;
        if (bn*128 < csplit){ dst = (u16*)C1; ld = ld1; }
        else { dst = (u16*)C2; ld = ld2; colbase -= csplit; }
        u16* gp = dst + (size_t)(bm*256+row)*ld + colbase;
        const u16* sp = Cs + row*136 + half*64;
        #pragma unroll
        for (int k2=0;k2<8;k2++) *(uint4*)(gp + k2*8) = *(const uint4*)(sp + k2*8);
    } else {
        #pragma unroll
        for (int i=0;i<4;i++)
            #pragma unroll
            for (int j=0;j<4;j++)
                #pragma unroll
                for (int r=0;r<4;r++){
                    int row = bm*256 + wm*64 + i*16 + lg*4 + r;
                    int col = bn*128 + wn*64 + j*16 + lr;
                    ((float*)C1)[(size_t)row*ld1 + col] = acc[i][j][r];
                }
    }
}

// ---------- ba = hidden @ W_ba ; be[].x = sigmoid(b), be[].y = g (log-decay) ----------
__global__ void k_ba(const float* __restrict__ hidden, const float* __restrict__ W_ba,
                     const float* __restrict__ dt_bias, const float* __restrict__ A_log,
                     float2* __restrict__ be){
    int row = blockIdx.x*8 + (threadIdx.x>>5);
    int col = threadIdx.x & 31;
    const float* h = hidden + (size_t)row*HID;
    float s0=0.f, s1=0.f, s2=0.f, s3=0.f;
    #pragma unroll 2
    for (int k=0;k<HID;k+=4){
        s0 = fmaf(h[k],   W_ba[(k)*32+col],   s0);
        s1 = fmaf(h[k+1], W_ba[(k+1)*32+col], s1);
        s2 = fmaf(h[k+2], W_ba[(k+2)*32+col], s2);
        s3 = fmaf(h[k+3], W_ba[(k+3)*32+col], s3);
    }
    float s = (s0+s1)+(s2+s3);
    if (col < NH){
        be[(size_t)row*NH + col].x = 1.f/(1.f+expf(-s));
    } else {
        int hh = col - NH;
        float x = s + dt_bias[hh];
        float sp = fmaxf(x,0.f) + log1pf(expf(-fabsf(x)));   // softplus, stable
        be[(size_t)row*NH + hh].y = -expf(A_log[hh])*sp;     // g (not exponentiated)
    }
}

// ---------- causal conv (KW=4) + bias + SiLU + fused q/k l2-norm ----------
// block = 8 consecutive t x 256 channels (rolling window; 1.375x read amp)
__global__ __launch_bounds__(256) void k_conv_silu(const u16* __restrict__ qkv, const float* __restrict__ conv_w,
                            const float* __restrict__ conv_b, u16* __restrict__ mixed){
    __shared__ float hsum[4][8];
    const int bid = blockIdx.x, tid = threadIdx.x;
    const int c0 = (bid % 24) << 8;
    const long bt0 = (long)(bid / 24) * 8;
    const int ts0 = (int)(bt0 % T_SEQ);          // multiple of 8
    const int c = c0 + tid;
    const u16* in = qkv + (size_t)bt0*CONV_CH + c;
    float4 w = *(const float4*)(conv_w + c*4);
    float bias = conv_b[c];
    float w0=0.f, w1=0.f, w2=0.f;
    if (ts0 > 0){
        w0 = bf2f(in[-3*CONV_CH]); w1 = bf2f(in[-2*CONV_CH]); w2 = bf2f(in[-1*CONV_CH]);
    }
    float sv[8];
    #pragma unroll
    for (int j=0;j<8;j++){
        float xc = bf2f(in[(ptrdiff_t)j*CONV_CH]);
        float acc = bias + w.x*w0 + w.y*w1 + w.z*w2 + w.w*xc;
        sv[j] = acc / (1.f + __expf(-acc));
        w0 = w1; w1 = w2; w2 = xc;
    }
    if (c0 < 2*KD){                               // q/k: fused l2-norm (block-uniform branch)
        float ss[8];
        #pragma unroll
        for (int j=0;j<8;j++) ss[j] = sv[j]*sv[j];
        #pragma unroll
        for (int m=1;m<64;m<<=1)
            #pragma unroll
            for (int j=0;j<8;j++) ss[j] += __shfl_xor(ss[j], m, 64);
        if ((tid&63)==0)
            #pragma unroll
            for (int j=0;j<8;j++) hsum[tid>>6][j] = ss[j];
        __syncthreads();
        int head = tid>>7;
        float qs = (c0 + head*128 < KD) ? 0.08838834764831845f : 1.f;
        #pragma unroll
        for (int j=0;j<8;j++){
            float tot = hsum[head*2][j] + hsum[head*2+1][j];
            sv[j] *= rsqrtf(tot + 1e-6f) * qs;
        }
    }
    u16* outp = mixed + (size_t)bt0*CONV_CH + c;
    #pragma unroll
    for (int j=0;j<8;j++) outp[(size_t)j*CONV_CH] = f2bf(sv[j]);
}

// ================= chunked delta rule =================
__global__ __launch_bounds__(512) void k_prep(const u16* __restrict__ mixed,
        const float2* __restrict__ be, u16* __restrict__ Wcg, u16* __restrict__ Ucg,
        float* __restrict__ barr){
    __shared__ __align__(16) u16 Ks[64*128];
    __shared__ __align__(16) u16 Vs[64*128];
    __shared__ float Am[64*64];
    __shared__ __align__(16) float RHS[64*256];
    __shared__ float bv[64], betav[64], lamv[64];
    const int tid = threadIdx.x;
    const int lane = tid & 63, wave = tid >> 6;
    const int lr = lane & 15, lg = lane >> 4;
    const int chunk = blockIdx.x;
    const int ci = chunk & 63, bh = chunk >> 6, b = bh >> 4, h = bh & 15;
    const size_t rowbase = (size_t)b*T_SEQ + ci*64;

    const u16* kg = mixed + rowbase*CONV_CH + KD + h*128;
    const u16* vg = mixed + rowbase*CONV_CH + 2*KD + h*128;
    #pragma unroll
    for (int pass=0; pass<2; pass++){
        int row = (tid>>4) + pass*32;
        int co = (tid&15)*8;
        gl_lds16(kg + (size_t)row*CONV_CH + co, Ks + row*128 + co);
        gl_lds16(vg + (size_t)row*CONV_CH + co, Vs + row*128 + co);
    }
    if (tid < 64){
        float2 bg = be[(rowbase + tid)*NH + h];
        float acc = bg.y;
        #pragma unroll
        for (int m=1;m<64;m<<=1){ float u = __shfl_up(acc, m, 64); if (tid >= m) acc += u; }
        bv[tid] = acc; betav[tid] = bg.x; lamv[tid] = __expf(acc);
        barr[(size_t)chunk*64 + tid] = acc;
    }
    __syncthreads();
    #pragma unroll
    for (int i=0;i<2;i++){
        int tile = wave*2 + i;
        int tm = tile>>2, tn = tile&3;
        f32x4 acc = {};
        #pragma unroll
        for (int kk=0;kk<4;kk++)
            acc = __builtin_amdgcn_mfma_f32_16x16x32_bf16(
                frag(Ks, tm*16+lr, 128, kk*32+lg*8),
                frag(Ks, tn*16+lr, 128, kk*32+lg*8), acc, 0,0,0);
        #pragma unroll
        for (int r=0;r<4;r++){
            int t = tm*16 + lg*4 + r, s = tn*16 + lr;
            Am[t*64+s] = (t>s) ? betav[t]*__expf(bv[t]-bv[s])*acc[r] : 0.f;
        }
    }
    __syncthreads();
    for (int i=tid; i<64*256; i+=512){
        int r = i>>8, j = i&255;
        RHS[i] = (j<128) ? betav[r]*lamv[r]*bf2f(Ks[r*128+j])
                         : betav[r]*bf2f(Vs[r*128 + (j-128)]);
    }
    __syncthreads();
    for (int blk=0; blk<8; blk++){
        int base = blk*8;
        if (base){
            int r = base + (tid>>6);
            int j0 = (tid&63)*4;
            float4 x = *(float4*)&RHS[r*256 + j0];
            for (int s=0; s<base; s++){
                float a = Am[r*64+s];
                float4 y = *(float4*)&RHS[s*256 + j0];
                x.x = fmaf(-a, y.x, x.x); x.y = fmaf(-a, y.y, x.y);
                x.z = fmaf(-a, y.z, x.z); x.w = fmaf(-a, y.w, x.w);
            }
            *(float4*)&RHS[r*256 + j0] = x;
        }
        __syncthreads();
        if (tid < 256){
            float x[8];
            #pragma unroll
            for (int i=0;i<8;i++) x[i] = RHS[(base+i)*256 + tid];
            #pragma unroll
            for (int r=1;r<8;r++)
                #pragma unroll
                for (int s=0;s<r;s++)
                    x[r] = fmaf(-Am[(base+r)*64 + base+s], x[s], x[r]);
            #pragma unroll
            for (int i=1;i<8;i++) RHS[(base+i)*256 + tid] = x[i];
        }
        __syncthreads();
    }
    for (int i=tid; i<8192; i+=512){
        int r = i>>7, c = i&127;
        Wcg[(size_t)chunk*8192 + i] = f2bf(RHS[r*256 + c]);
        Ucg[(size_t)chunk*8192 + i] = f2bf(RHS[r*256 + 128 + c]);
    }
}

// ---------- sequential chunk recurrence + fused o1 = diag(e^b) Q @ S0 ----------
__global__ __launch_bounds__(256) void k_seq(const u16* __restrict__ mixed,
        const u16* __restrict__ Wcg, const u16* __restrict__ Ucg,
        const float* __restrict__ barr,
        float* __restrict__ o1g, u16* __restrict__ DTg){
    __shared__ __align__(16) u16 WcS[2][64*128];
    __shared__ __align__(16) u16 Ks[2][64*128];
    __shared__ __align__(16) u16 Qs[2][64*128];
    __shared__ __align__(16) u16 UcS[2][64*32];
    __shared__ __align__(16) u16 KpT[128*72];
    __shared__ __align__(16) u16 DT[32*72];
    __shared__ __align__(16) u16 STh[32*136];
    __shared__ __align__(16) u16 STl[32*136];
    __shared__ float bvv[2][64], esc[64];
    const int tid = threadIdx.x, lane = tid&63, wave = tid>>6;
    const int lr = lane&15, lg = lane>>4;
    const int blk = blockIdx.x;
    const int bh = blk & 31, vs = blk >> 5;
    const int b = bh>>4, h = bh&15, v0 = vs*32;
    const u16* qgb = mixed + (size_t)b*T_SEQ*CONV_CH + h*128;
    const u16* kgb = qgb + KD;
    const int urow = tid>>2, uc8 = (tid&3)*8;

    float sreg[4][4];
    #pragma unroll
    for (int i=0;i<4;i++)
        #pragma unroll
        for (int r=0;r<4;r++) sreg[i][r] = 0.f;
    for (int i=tid; i<32*136; i+=256){ STh[i]=0; STl[i]=0; }

    auto STAGE = [&](int ci2, int bf){
        const size_t ch = (size_t)(bh*64 + ci2);
        #pragma unroll
        for (int pass=0; pass<4; pass++){
            gl_lds16(Wcg + ch*8192 + pass*2048 + tid*8, &WcS[bf][pass*2048 + tid*8]);
            int row = pass*16 + (tid>>4), co = (tid&15)*8;
            gl_lds16(kgb + ((size_t)(ci2*64) + row)*CONV_CH + co, &Ks[bf][row*128 + co]);
            gl_lds16(qgb + ((size_t)(ci2*64) + row)*CONV_CH + co, &Qs[bf][row*128 + co]);
        }
    };

    STAGE(0, 0);
    *(uint4*)&UcS[0][urow*32 + uc8] = *(const uint4*)(Ucg + (size_t)(bh*64)*8192 + urow*128 + v0 + uc8);
    if (tid<64) bvv[0][tid] = barr[(size_t)(bh*64)*64 + tid];
    __syncthreads();

    for (int ci=0; ci<64; ci++){
        const int cur = ci&1, nxt = cur^1;
        const size_t chunk = (size_t)(bh*64 + ci);
        const size_t rowbase = (size_t)b*T_SEQ + ci*64;
        uint4 ucv = {0,0,0,0}; float bvn = 0.f;
        const bool havenext = (ci+1 < 64);
        if (havenext){
            STAGE(ci+1, nxt);
            ucv = *(const uint4*)(Ucg + (chunk+1)*8192 + urow*128 + v0 + uc8);
            if (tid<64) bvn = barr[(chunk+1)*64 + tid];
        }
        if (tid<64) esc[tid] = __expf(bvv[cur][63] - bvv[cur][tid]);
        // Delta = Uc - Wc@S0 -> DT [v][t]
        #pragma unroll
        for (int i=0;i<2;i++){
            int tile = wave*2 + i, tm = tile>>1, tn = tile&1;
            f32x4 acc = {};
            #pragma unroll
            for (int kk=0;kk<4;kk++){
                bf16x8 af = frag(WcS[cur], tm*16+lr, 128, kk*32+lg*8);
                acc = __builtin_amdgcn_mfma_f32_16x16x32_bf16(af, frag(STh, tn*16+lr, 136, kk*32+lg*8), acc, 0,0,0);
                acc = __builtin_amdgcn_mfma_f32_16x16x32_bf16(af, frag(STl, tn*16+lr, 136, kk*32+lg*8), acc, 0,0,0);
            }
            #pragma unroll
            for (int r=0;r<4;r++){
                int t = tm*16+lg*4+r, vv = tn*16+lr;
                DT[vv*72 + t] = f2bf(bf2f(UcS[cur][t*32+vv]) - acc[r]);
            }
        }
        // o1 = e^{b_t} * (Q @ S0)
        #pragma unroll
        for (int i=0;i<2;i++){
            int tile = wave*2 + i, tm = tile>>1, tn = tile&1;
            f32x4 acc = {};
            #pragma unroll
            for (int kk=0;kk<4;kk++){
                bf16x8 af = frag(Qs[cur], tm*16+lr, 128, kk*32+lg*8);
                acc = __builtin_amdgcn_mfma_f32_16x16x32_bf16(af, frag(STh, tn*16+lr, 136, kk*32+lg*8), acc, 0,0,0);
                acc = __builtin_amdgcn_mfma_f32_16x16x32_bf16(af, frag(STl, tn*16+lr, 136, kk*32+lg*8), acc, 0,0,0);
            }
            #pragma unroll
            for (int r=0;r<4;r++){
                int t = tm*16+lg*4+r, vv = tn*16+lr;
                o1g[((rowbase + t)*NH + h)*DKH + v0 + vv] = acc[r]*__expf(bvv[cur][t]);
            }
        }
        __syncthreads();
        for (int i=tid; i<8192; i+=256){
            int t = i>>7, k = i&127;
            KpT[(size_t)k*72 + t] = f2bf(bf2f(Ks[cur][t*128 + k]) * esc[t]);
        }
        { int vv = tid>>3, c = (tid&7)*8;
          *(uint4*)(DTg + chunk*8192 + (size_t)(v0+vv)*64 + c) = *(const uint4*)&DT[vv*72 + c]; }
        if (havenext){
            *(uint4*)&UcS[nxt][urow*32 + uc8] = ucv;
            if (tid<64) bvv[nxt][tid] = bvn;
        }
        __syncthreads();
        float lamC = __expf(bvv[cur][63]);
        #pragma unroll
        for (int i=0;i<4;i++){
            int tile = wave*4 + i, tm = tile>>1, tn = tile&1;
            f32x4 acc;
            #pragma unroll
            for (int r=0;r<4;r++) acc[r] = lamC * sreg[i][r];
            #pragma unroll
            for (int kk=0;kk<2;kk++)
                acc = __builtin_amdgcn_mfma_f32_16x16x32_bf16(
                    frag(KpT, tm*16+lr, 72, kk*32+lg*8),
                    frag(DT,  tn*16+lr, 72, kk*32+lg*8), acc, 0,0,0);
            #pragma unroll
            for (int r=0;r<4;r++){
                int k = tm*16+lg*4+r, vv = tn*16+lr;
                sreg[i][r] = acc[r];
                u16 hi = f2bf(acc[r]);
                STh[vv*136 + k] = hi;
                STl[vv*136 + k] = f2bf(acc[r] - bf2f(hi));
            }
        }
        __syncthreads();
    }
}

// ---------- o = o1 + QKmask @ Delta ----------
__global__ __launch_bounds__(256) void k_out(const u16* __restrict__ mixed,
        const float* __restrict__ barr, const float* __restrict__ o1g,
        const u16* __restrict__ DTg, float* __restrict__ o){
    __shared__ __align__(16) u16 Qs[64*128];
    __shared__ __align__(16) u16 Ks[64*128];
    __shared__ __align__(16) u16 DTs[128*64];
    __shared__ __align__(16) u16 QKm[64*72];
    __shared__ float bvv[64];
    const int tid = threadIdx.x, lane = tid&63, wave = tid>>6;
    const int lr = lane&15, lg = lane>>4;
    const int chunk = blockIdx.x;
    const int ci = chunk&63, bh = chunk>>6, b = bh>>4, h = bh&15;
    const size_t rowbase = (size_t)b*T_SEQ + ci*64;
    const u16* qg = mixed + rowbase*CONV_CH + h*128;
    const u16* kg = qg + KD;
    #pragma unroll
    for (int pass=0; pass<4; pass++){
        int row = pass*16 + (tid>>4), co = (tid&15)*8;
        gl_lds16(qg + (size_t)row*CONV_CH + co, Qs + row*128 + co);
        gl_lds16(kg + (size_t)row*CONV_CH + co, Ks + row*128 + co);
        gl_lds16(DTg + (size_t)chunk*8192 + pass*2048 + tid*8, DTs + pass*2048 + tid*8);
    }
    if (tid<64) bvv[tid] = barr[(size_t)chunk*64 + tid];
    __syncthreads();
    {
        f32x4 acc[4];
        #pragma unroll
        for (int tn=0; tn<4; tn++){
            f32x4 a = {};
            #pragma unroll
            for (int kk=0;kk<4;kk++)
                a = __builtin_amdgcn_mfma_f32_16x16x32_bf16(
                    frag(Qs, wave*16+lr, 128, kk*32+lg*8),
                    frag(Ks, tn*16+lr, 128, kk*32+lg*8), a, 0,0,0);
            acc[tn] = a;
        }
        #pragma unroll
        for (int tn=0;tn<4;tn++)
            #pragma unroll
            for (int r=0;r<4;r++){
                int t = wave*16+lg*4+r, s = tn*16+lr;
                float val = (t>=s) ? acc[tn][r]*__expf(bvv[t]-bvv[s]) : 0.f;
                QKm[t*72+s] = f2bf(val);
            }
    }
    __syncthreads();
    f32x4 acc[8] = {};
    #pragma unroll
    for (int kk=0;kk<2;kk++){
        bf16x8 af = frag(QKm, wave*16+lr, 72, kk*32+lg*8);
        #pragma unroll
        for (int tn=0;tn<8;tn++)
            acc[tn] = __builtin_amdgcn_mfma_f32_16x16x32_bf16(af, frag(DTs, tn*16+lr, 64, kk*32+lg*8), acc[tn], 0,0,0);
    }
    #pragma unroll
    for (int tn=0;tn<8;tn++)
        #pragma unroll
        for (int r=0;r<4;r++){
            int t = wave*16+lg*4+r, v = tn*16+lr;
            size_t idx = ((rowbase + t)*NH + h)*DKH + v;
            o[idx] = o1g[idx] + acc[tn][r];
        }
}

// ---------- x = RMSNorm(o * silu(z)) * norm_w, cast bf16 ----------
__global__ void k_gatenorm(const float* __restrict__ o, const u16* __restrict__ zbuf,
                           const float* __restrict__ norm_w, u16* __restrict__ x){
    int gw   = blockIdx.x*4 + (threadIdx.x>>6);
    int lane = threadIdx.x & 63;
    int bt = gw >> 4, h = gw & 15;
    const float* opr = o + ((size_t)bt*NH + h)*DKH + lane*2;
    const u16* zp = zbuf + (size_t)bt*VD + h*DKH + lane*2;
    float o0 = opr[0], o1 = opr[1];
    u32 zu = *(const u32*)zp;
    float z0 = bflo(zu), z1 = bfhi(zu);
    float x0 = o0 * (z0/(1.f+__expf(-z0)));
    float x1 = o1 * (z1/(1.f+__expf(-z1)));
    float ss = x0*x0 + x1*x1;
    #pragma unroll
    for (int m=1;m<64;m<<=1) ss += __shfl_xor(ss, m, 64);
    float sc = rsqrtf(ss*(1.f/128.f) + 1e-6f);
    x0 *= sc*norm_w[lane*2]; x1 *= sc*norm_w[lane*2+1];
    ((u32*)x)[(size_t)bt*(VD/2) + h*(DKH/2) + lane] = (u32)f2bf(x0) | ((u32)f2bf(x1)<<16);
}

extern "C" void kernel_launch(void* const* d_in, const int* in_sizes, int n_in,
                              void* d_out, int out_size, void* d_ws, size_t ws_size,
                              hipStream_t stream){
    (void)in_sizes; (void)n_in; (void)out_size; (void)ws_size;
    const float* hidden = (const float*)d_in[0];
    const float* W_qkvz = (const float*)d_in[1];
    const float* W_ba   = (const float*)d_in[2];
    const float* conv_w = (const float*)d_in[3];
    const float* conv_b = (const float*)d_in[4];
    const float* dt_bias= (const float*)d_in[5];
    const float* A_log  = (const float*)d_in[6];
    const float* norm_w = (const float*)d_in[7];
    const float* W_out  = (const float*)d_in[8];
    float* out = (float*)d_out;

    char* ws = (char*)d_ws;
    size_t off = 0;
    auto alloc = [&](size_t bytes)->char*{ char* p = ws + off; off += (bytes + 255) & ~(size_t)255; return p; };
    // Pool A (100.66 MB): h_bf|WqT -> Wcg|Ucg|DTg -> o|DTg
    char* poolA = alloc(100663296);
    u16*   h_bf = (u16*)poolA;
    u16*   WqT  = (u16*)(poolA + 50331648);
    u16*   Wcg  = (u16*)poolA;
    u16*   Ucg  = (u16*)(poolA + 33554432);
    u16*   DTg  = (u16*)(poolA + 67108864);
    float* o_b  = (float*)poolA;
    // Pool B (100.66 MB): qkv_lin -> o1g|barr -> x|barr
    char* poolB = alloc(100663296);
    u16*   qkv_lin = (u16*)poolB;
    float* o1g  = (float*)poolB;
    float* barr = (float*)(poolB + 67108864);
    u16*   x_b  = (u16*)poolB;
    u16*   WoT  = (u16*)  alloc((size_t)HID*VD*2);        // 12.6 MB
    u16*   zbuf = (u16*)  alloc((size_t)MROWS*VD*2);      // 33.55 MB
    u16*   mixed= (u16*)  alloc((size_t)MROWS*CONV_CH*2); // 100.66 MB
    float2* be_b= (float2*)alloc((size_t)MROWS*NH*8);     // 1.05 MB
    // total 349.2 MB == proven footprint

    k_cast<<<2048,256,0,stream>>>(hidden, h_bf, MROWS*HID/4);
    k_transpose_cast<<<(HID/32)*(N_QKVZ/32),256,0,stream>>>(W_qkvz, WqT, HID, N_QKVZ);
    k_transpose_cast<<<(VD/32)*(HID/32),256,0,stream>>>(W_out, WoT, VD, HID);
    k_gemm3<true><<<(MROWS/256)*(N_QKVZ/128),512,0,stream>>>(h_bf, WqT, qkv_lin, zbuf,
                         MROWS, N_QKVZ, HID, CONV_CH, CONV_CH, VD);
    k_ba<<<MROWS/8,256,0,stream>>>(hidden, W_ba, dt_bias, A_log, be_b);
    k_conv_silu<<<(MROWS/8)*24,256,0,stream>>>(qkv_lin, conv_w, conv_b, mixed);
    k_prep<<<2048,512,0,stream>>>(mixed, be_b, Wcg, Ucg, barr);
    k_seq<<<128,256,0,stream>>>(mixed, Wcg, Ucg, barr, o1g, DTg);
    k_out<<<2048,256,0,stream>>>(mixed, barr, o1g, DTg, o_b);
    k_gatenorm<<<MROWS*NH/4,256,0,stream>>>(o_b, zbuf, norm_w, x_b);
    k_gemm3<false><<<(MROWS/256)*(HID/128),512,0,stream>>>(x_b, WoT, out, nullptr,
                         MROWS, HID, VD, 1<<30, HID, 0);
}

// Round 11
// 1355.125 us; speedup vs baseline: 1.2238x; 1.2238x over previous
//
#include <hip/hip_runtime.h>
#include <cstdint>
#include <cstddef>

#define T_SEQ 4096
#define HID 3072
#define NH 16
#define DKH 128
#define KD 2048
#define VD 2048
#define N_QKVZ 8192
#define CONV_CH 6144
#define MROWS 8192  // B*T

typedef unsigned short u16;
typedef unsigned int u32;

typedef __attribute__((ext_vector_type(8))) short bf16x8;
typedef __attribute__((ext_vector_type(4))) float f32x4;

__device__ __forceinline__ float bf2f(u16 u){ u32 t=((u32)u)<<16; float f; __builtin_memcpy(&f,&t,4); return f; }
__device__ __forceinline__ float bflo(u32 u){ u32 t=u<<16; float f; __builtin_memcpy(&f,&t,4); return f; }
__device__ __forceinline__ float bfhi(u32 u){ u32 t=u&0xffff0000u; float f; __builtin_memcpy(&f,&t,4); return f; }
__device__ __forceinline__ u16 f2bf(float f){ u32 i; __builtin_memcpy(&i,&f,4); return (u16)((i + 0x7fffu + ((i>>16)&1u))>>16); }

__device__ __forceinline__ void gl_lds16(const u16* g, u16* l){
    __builtin_amdgcn_global_load_lds(
        (const __attribute__((address_space(1))) void*)g,
        (__attribute__((address_space(3))) void*)l, 16, 0, 0);
}

__device__ __forceinline__ bf16x8 frag(const u16* p, int row, int stride, int k0){
    return *(const bf16x8*)(p + (size_t)row*stride + k0);
}

// ---------- cast f32 -> bf16 (flat) ----------
__global__ void k_cast(const float* __restrict__ in, u16* __restrict__ out, int n4){
    int stride = gridDim.x*blockDim.x;
    for (int i = blockIdx.x*blockDim.x + threadIdx.x; i < n4; i += stride){
        float4 v = ((const float4*)in)[i];
        u32 lo = (u32)f2bf(v.x) | ((u32)f2bf(v.y)<<16);
        u32 hi = (u32)f2bf(v.z) | ((u32)f2bf(v.w)<<16);
        ((uint2*)out)[i] = make_uint2(lo,hi);
    }
}

// ---------- transpose + cast: in[R][C] f32 -> out[C][R] bf16 ----------
__global__ void k_transpose_cast(const float* __restrict__ in, u16* __restrict__ out, int R, int C){
    __shared__ u16 tile[32][33];
    int nbc = C >> 5;
    int bc = blockIdx.x % nbc, br = blockIdx.x / nbc;
    int c0 = bc<<5, r0 = br<<5;
    int tx = threadIdx.x & 31, ty = threadIdx.x >> 5;
    #pragma unroll
    for (int i=0;i<4;i++){
        int r = ty + i*8;
        tile[r][tx] = f2bf(in[(size_t)(r0+r)*C + c0 + tx]);
    }
    __syncthreads();
    #pragma unroll
    for (int i=0;i<4;i++){
        int r = ty + i*8;
        out[(size_t)(c0+r)*R + r0 + tx] = tile[tx][r];
    }
}

// ---------- bf16 MFMA GEMM, 128x128 tile, dbuf stage-first, grouped order, LDS epilogue ----------
template<bool OUT_BF16>
__global__ __launch_bounds__(256, 2) void k_gemm_bt(const u16* __restrict__ A, const u16* __restrict__ Bt,
                                                 void* __restrict__ C1, void* __restrict__ C2,
                                                 int M, int N, int K, int csplit, int ld1, int ld2){
    __shared__ __align__(16) u16 SM[4*128*64];   // 64 KB: As[2] | Bs[2]; reused as epilogue buffer
    u16 (*As)[128*64] = (u16(*)[128*64])SM;
    u16 (*Bs)[128*64] = (u16(*)[128*64])(SM + 2*128*64);
    const int tid  = threadIdx.x;
    const int lane = tid & 63;
    const int wave = tid >> 6;
    const int wm = (wave >> 1) << 6;
    const int wn = (wave & 1) << 6;
    const int lr = lane & 15, lg = lane >> 4;
    const int nbn = N >> 7;
    const int per = 8*nbn;
    const int grp = blockIdx.x / per, rem = blockIdx.x % per;
    const int bm = grp*8 + (rem & 7);
    const int bn = rem >> 3;
    f32x4 acc[4][4] = {};
    const size_t aRow0 = (size_t)bm*128;
    const size_t bRow0 = (size_t)bn*128;
    const int srow = wave*32 + (lane>>3);
    const int scol = (lane&7)*8;

    auto STAGE = [&](int kt, int b){
        const u16* ga = A  + (aRow0 + srow)*K + kt + scol;
        const u16* gb = Bt + (bRow0 + srow)*K + kt + scol;
        u16* la = &As[b][wave*2048];
        u16* lb = &Bs[b][wave*2048];
        #pragma unroll
        for (int i=0;i<4;i++){
            gl_lds16(ga + (size_t)i*8*K, la + i*512);
            gl_lds16(gb + (size_t)i*8*K, lb + i*512);
        }
    };

    STAGE(0, 0);
    __syncthreads();

    const int NT = K >> 6;
    int cur = 0;
    for (int t = 0; t < NT; t++){
        if (t+1 < NT) STAGE((t+1)*64, cur^1);
        #pragma unroll
        for (int kk=0; kk<2; kk++){
            bf16x8 af[4], bfv[4];
            #pragma unroll
            for (int i=0;i<4;i++){
                af[i]  = *(const bf16x8*)&As[cur][((wm + i*16 + lr)<<6) + (kk<<5) + (lg<<3)];
                bfv[i] = *(const bf16x8*)&Bs[cur][((wn + i*16 + lr)<<6) + (kk<<5) + (lg<<3)];
            }
            __builtin_amdgcn_s_setprio(1);
            #pragma unroll
            for (int i=0;i<4;i++)
                #pragma unroll
                for (int j=0;j<4;j++)
                    acc[i][j] = __builtin_amdgcn_mfma_f32_16x16x32_bf16(af[i], bfv[j], acc[i][j], 0, 0, 0);
            __builtin_amdgcn_s_setprio(0);
        }
        __syncthreads();
        cur ^= 1;
    }

    if (OUT_BF16){
        u16* Cs = SM;                       // 128*136*2 = 34816 B
        #pragma unroll
        for (int i=0;i<4;i++)
            #pragma unroll
            for (int j=0;j<4;j++)
                #pragma unroll
                for (int r=0;r<4;r++)
                    Cs[(wm + i*16 + lg*4 + r)*136 + wn + j*16 + lr] = f2bf(acc[i][j][r]);
        __syncthreads();
        int row = tid >> 1, half = tid & 1;
        int colbase = bn*128 + half*64;
        u16* dst; int ld;
        if (bn*128 < csplit){ dst = (u16*)C1; ld = ld1; }
        else { dst = (u16*)C2; ld = ld2; colbase -= csplit; }
        u16* gp = dst + (size_t)(bm*128+row)*ld + colbase;
        const u16* sp = Cs + row*136 + half*64;
        #pragma unroll
        for (int k2=0;k2<8;k2++) *(uint4*)(gp + k2*8) = *(const uint4*)(sp + k2*8);
    } else {
        #pragma unroll
        for (int i=0;i<4;i++)
            #pragma unroll
            for (int j=0;j<4;j++)
                #pragma unroll
                for (int r=0;r<4;r++){
                    int row = bm*128 + wm + i*16 + lg*4 + r;
                    int col = bn*128 + wn + j*16 + lr;
                    ((float*)C1)[(size_t)row*ld1 + col] = acc[i][j][r];
                }
    }
}

// ---------- ba = hidden @ W_ba ; be[].x = sigmoid(b), be[].y = g (log-decay) ----------
__global__ void k_ba(const float* __restrict__ hidden, const float* __restrict__ W_ba,
                     const float* __restrict__ dt_bias, const float* __restrict__ A_log,
                     float2* __restrict__ be){
    int row = blockIdx.x*8 + (threadIdx.x>>5);
    int col = threadIdx.x & 31;
    const float* h = hidden + (size_t)row*HID;
    float s0=0.f, s1=0.f, s2=0.f, s3=0.f;
    #pragma unroll 2
    for (int k=0;k<HID;k+=4){
        s0 = fmaf(h[k],   W_ba[(k)*32+col],   s0);
        s1 = fmaf(h[k+1], W_ba[(k+1)*32+col], s1);
        s2 = fmaf(h[k+2], W_ba[(k+2)*32+col], s2);
        s3 = fmaf(h[k+3], W_ba[(k+3)*32+col], s3);
    }
    float s = (s0+s1)+(s2+s3);
    if (col < NH){
        be[(size_t)row*NH + col].x = 1.f/(1.f+expf(-s));
    } else {
        int hh = col - NH;
        float x = s + dt_bias[hh];
        float sp = fmaxf(x,0.f) + log1pf(expf(-fabsf(x)));   // softplus, stable
        be[(size_t)row*NH + hh].y = -expf(A_log[hh])*sp;     // g (not exponentiated)
    }
}

// ---------- causal conv (KW=4) + bias + SiLU + fused q/k l2-norm ----------
// block = 8 consecutive t x 256 channels (rolling window; 1.375x read amp)
__global__ __launch_bounds__(256) void k_conv_silu(const u16* __restrict__ qkv, const float* __restrict__ conv_w,
                            const float* __restrict__ conv_b, u16* __restrict__ mixed){
    __shared__ float hsum[4][8];
    const int bid = blockIdx.x, tid = threadIdx.x;
    const int c0 = (bid % 24) << 8;
    const long bt0 = (long)(bid / 24) * 8;
    const int ts0 = (int)(bt0 % T_SEQ);          // multiple of 8
    const int c = c0 + tid;
    const u16* in = qkv + (size_t)bt0*CONV_CH + c;
    float4 w = *(const float4*)(conv_w + c*4);
    float bias = conv_b[c];
    float w0=0.f, w1=0.f, w2=0.f;
    if (ts0 > 0){
        w0 = bf2f(in[-3*CONV_CH]); w1 = bf2f(in[-2*CONV_CH]); w2 = bf2f(in[-1*CONV_CH]);
    }
    float sv[8];
    #pragma unroll
    for (int j=0;j<8;j++){
        float xc = bf2f(in[(ptrdiff_t)j*CONV_CH]);
        float acc = bias + w.x*w0 + w.y*w1 + w.z*w2 + w.w*xc;
        sv[j] = acc / (1.f + __expf(-acc));
        w0 = w1; w1 = w2; w2 = xc;
    }
    if (c0 < 2*KD){                               // q/k: fused l2-norm (block-uniform branch)
        float ss[8];
        #pragma unroll
        for (int j=0;j<8;j++) ss[j] = sv[j]*sv[j];
        #pragma unroll
        for (int m=1;m<64;m<<=1)
            #pragma unroll
            for (int j=0;j<8;j++) ss[j] += __shfl_xor(ss[j], m, 64);
        if ((tid&63)==0)
            #pragma unroll
            for (int j=0;j<8;j++) hsum[tid>>6][j] = ss[j];
        __syncthreads();
        int head = tid>>7;
        float qs = (c0 + head*128 < KD) ? 0.08838834764831845f : 1.f;
        #pragma unroll
        for (int j=0;j<8;j++){
            float tot = hsum[head*2][j] + hsum[head*2+1][j];
            sv[j] *= rsqrtf(tot + 1e-6f) * qs;
        }
    }
    u16* outp = mixed + (size_t)bt0*CONV_CH + c;
    #pragma unroll
    for (int j=0;j<8;j++) outp[(size_t)j*CONV_CH] = f2bf(sv[j]);
}

// ================= chunked delta rule =================
__global__ __launch_bounds__(512) void k_prep(const u16* __restrict__ mixed,
        const float2* __restrict__ be, u16* __restrict__ Wcg, u16* __restrict__ Ucg,
        float* __restrict__ barr){
    __shared__ __align__(16) u16 Ks[64*128];
    __shared__ __align__(16) u16 Vs[64*128];
    __shared__ float Am[64*64];
    __shared__ __align__(16) float RHS[64*256];
    __shared__ float bv[64], betav[64], lamv[64];
    const int tid = threadIdx.x;
    const int lane = tid & 63, wave = tid >> 6;
    const int lr = lane & 15, lg = lane >> 4;
    const int chunk = blockIdx.x;
    const int ci = chunk & 63, bh = chunk >> 6, b = bh >> 4, h = bh & 15;
    const size_t rowbase = (size_t)b*T_SEQ + ci*64;

    const u16* kg = mixed + rowbase*CONV_CH + KD + h*128;
    const u16* vg = mixed + rowbase*CONV_CH + 2*KD + h*128;
    #pragma unroll
    for (int pass=0; pass<2; pass++){
        int row = (tid>>4) + pass*32;
        int co = (tid&15)*8;
        gl_lds16(kg + (size_t)row*CONV_CH + co, Ks + row*128 + co);
        gl_lds16(vg + (size_t)row*CONV_CH + co, Vs + row*128 + co);
    }
    if (tid < 64){
        float2 bg = be[(rowbase + tid)*NH + h];
        float acc = bg.y;
        #pragma unroll
        for (int m=1;m<64;m<<=1){ float u = __shfl_up(acc, m, 64); if (tid >= m) acc += u; }
        bv[tid] = acc; betav[tid] = bg.x; lamv[tid] = __expf(acc);
        barr[(size_t)chunk*64 + tid] = acc;
    }
    __syncthreads();
    #pragma unroll
    for (int i=0;i<2;i++){
        int tile = wave*2 + i;
        int tm = tile>>2, tn = tile&3;
        f32x4 acc = {};
        #pragma unroll
        for (int kk=0;kk<4;kk++)
            acc = __builtin_amdgcn_mfma_f32_16x16x32_bf16(
                frag(Ks, tm*16+lr, 128, kk*32+lg*8),
                frag(Ks, tn*16+lr, 128, kk*32+lg*8), acc, 0,0,0);
        #pragma unroll
        for (int r=0;r<4;r++){
            int t = tm*16 + lg*4 + r, s = tn*16 + lr;
            Am[t*64+s] = (t>s) ? betav[t]*__expf(bv[t]-bv[s])*acc[r] : 0.f;
        }
    }
    __syncthreads();
    for (int i=tid; i<64*256; i+=512){
        int r = i>>8, j = i&255;
        RHS[i] = (j<128) ? betav[r]*lamv[r]*bf2f(Ks[r*128+j])
                         : betav[r]*bf2f(Vs[r*128 + (j-128)]);
    }
    __syncthreads();
    for (int blk=0; blk<8; blk++){
        int base = blk*8;
        if (base){
            int r = base + (tid>>6);
            int j0 = (tid&63)*4;
            float4 x = *(float4*)&RHS[r*256 + j0];
            for (int s=0; s<base; s++){
                float a = Am[r*64+s];
                float4 y = *(float4*)&RHS[s*256 + j0];
                x.x = fmaf(-a, y.x, x.x); x.y = fmaf(-a, y.y, x.y);
                x.z = fmaf(-a, y.z, x.z); x.w = fmaf(-a, y.w, x.w);
            }
            *(float4*)&RHS[r*256 + j0] = x;
        }
        __syncthreads();
        if (tid < 256){
            float x[8];
            #pragma unroll
            for (int i=0;i<8;i++) x[i] = RHS[(base+i)*256 + tid];
            #pragma unroll
            for (int r=1;r<8;r++)
                #pragma unroll
                for (int s=0;s<r;s++)
                    x[r] = fmaf(-Am[(base+r)*64 + base+s], x[s], x[r]);
            #pragma unroll
            for (int i=1;i<8;i++) RHS[(base+i)*256 + tid] = x[i];
        }
        __syncthreads();
    }
    for (int i=tid; i<8192; i+=512){
        int r = i>>7, c = i&127;
        Wcg[(size_t)chunk*8192 + i] = f2bf(RHS[r*256 + c]);
        Ucg[(size_t)chunk*8192 + i] = f2bf(RHS[r*256 + 128 + c]);
    }
}

// ---------- sequential chunk recurrence + fused o1 = diag(e^b) Q @ S0 ----------
// grid 256: blk = vs*32 + bh, 8 v-splits of 16 columns each; S in registers.
__global__ __launch_bounds__(256) void k_seq(const u16* __restrict__ mixed,
        const u16* __restrict__ Wcg, const u16* __restrict__ Ucg,
        const float* __restrict__ barr,
        float* __restrict__ o1g, u16* __restrict__ DTg){
    __shared__ __align__(16) u16 WcS[2][64*128];
    __shared__ __align__(16) u16 Ks[2][64*128];
    __shared__ __align__(16) u16 Qs[2][64*128];
    __shared__ __align__(16) u16 UcS[2][64*16];
    __shared__ __align__(16) u16 KpT[128*72];
    __shared__ __align__(16) u16 DT[16*72];
    __shared__ __align__(16) u16 STh[16*136];
    __shared__ __align__(16) u16 STl[16*136];
    __shared__ float bvv[2][64], esc[64];
    const int tid = threadIdx.x, lane = tid&63, wave = tid>>6;
    const int lr = lane&15, lg = lane>>4;
    const int blk = blockIdx.x;
    const int bh = blk & 31, vs = blk >> 5;       // vs 0..7
    const int b = bh>>4, h = bh&15, v0 = vs*16;
    const u16* qgb = mixed + (size_t)b*T_SEQ*CONV_CH + h*128;
    const u16* kgb = qgb + KD;

    float sreg[2][4];
    #pragma unroll
    for (int i=0;i<2;i++)
        #pragma unroll
        for (int r=0;r<4;r++) sreg[i][r] = 0.f;
    for (int i=tid; i<16*136; i+=256){ STh[i]=0; STl[i]=0; }

    auto STAGE = [&](int ci2, int bf){
        const size_t ch = (size_t)(bh*64 + ci2);
        #pragma unroll
        for (int pass=0; pass<4; pass++){
            gl_lds16(Wcg + ch*8192 + pass*2048 + tid*8, &WcS[bf][pass*2048 + tid*8]);
            int row = pass*16 + (tid>>4), co = (tid&15)*8;
            gl_lds16(kgb + ((size_t)(ci2*64) + row)*CONV_CH + co, &Ks[bf][row*128 + co]);
            gl_lds16(qgb + ((size_t)(ci2*64) + row)*CONV_CH + co, &Qs[bf][row*128 + co]);
        }
    };

    STAGE(0, 0);
    if (tid < 128){
        int row = tid>>1, c8 = (tid&1)*8;
        *(uint4*)&UcS[0][row*16 + c8] = *(const uint4*)(Ucg + (size_t)(bh*64)*8192 + (size_t)row*128 + v0 + c8);
    }
    if (tid<64) bvv[0][tid] = barr[(size_t)(bh*64)*64 + tid];
    __syncthreads();

    for (int ci=0; ci<64; ci++){
        const int cur = ci&1, nxt = cur^1;
        const size_t chunk = (size_t)(bh*64 + ci);
        const size_t rowbase = (size_t)b*T_SEQ + ci*64;
        uint4 ucv = {0,0,0,0}; float bvn = 0.f;
        const bool havenext = (ci+1 < 64);
        if (havenext){
            STAGE(ci+1, nxt);
            if (tid < 128)
                ucv = *(const uint4*)(Ucg + (chunk+1)*8192 + (size_t)(tid>>1)*128 + v0 + (tid&1)*8);
            if (tid<64) bvn = barr[(chunk+1)*64 + tid];
        }
        if (tid<64) esc[tid] = __expf(bvv[cur][63] - bvv[cur][tid]);
        // Delta = Uc - Wc@S0 -> DT [v][t]  (1 tile per wave: tm=wave, tn=0)
        {
            const int tm = wave;
            f32x4 acc = {};
            #pragma unroll
            for (int kk=0;kk<4;kk++){
                bf16x8 af = frag(WcS[cur], tm*16+lr, 128, kk*32+lg*8);
                acc = __builtin_amdgcn_mfma_f32_16x16x32_bf16(af, frag(STh, lr, 136, kk*32+lg*8), acc, 0,0,0);
                acc = __builtin_amdgcn_mfma_f32_16x16x32_bf16(af, frag(STl, lr, 136, kk*32+lg*8), acc, 0,0,0);
            }
            #pragma unroll
            for (int r=0;r<4;r++){
                int t = tm*16+lg*4+r;
                DT[lr*72 + t] = f2bf(bf2f(UcS[cur][t*16+lr]) - acc[r]);
            }
        }
        // o1 = e^{b_t} * (Q @ S0)  (1 tile per wave)
        {
            const int tm = wave;
            f32x4 acc = {};
            #pragma unroll
            for (int kk=0;kk<4;kk++){
                bf16x8 af = frag(Qs[cur], tm*16+lr, 128, kk*32+lg*8);
                acc = __builtin_amdgcn_mfma_f32_16x16x32_bf16(af, frag(STh, lr, 136, kk*32+lg*8), acc, 0,0,0);
                acc = __builtin_amdgcn_mfma_f32_16x16x32_bf16(af, frag(STl, lr, 136, kk*32+lg*8), acc, 0,0,0);
            }
            #pragma unroll
            for (int r=0;r<4;r++){
                int t = tm*16+lg*4+r;
                o1g[((rowbase + t)*NH + h)*DKH + v0 + lr] = acc[r]*__expf(bvv[cur][t]);
            }
        }
        __syncthreads();
        // KpT[k][t] = K[t][k]*esc[t]  (u32-packed writes: 16 iterations)
        for (int i=tid; i<4096; i+=256){
            int k = i & 127, t = (i >> 7) * 2;
            u32 pack = (u32)f2bf(bf2f(Ks[cur][t*128 + k]) * esc[t])
                     | ((u32)f2bf(bf2f(Ks[cur][(t+1)*128 + k]) * esc[t+1]) << 16);
            *(u32*)&KpT[(size_t)k*72 + t] = pack;
        }
        if (tid < 128){
            int vv = tid>>3, c = (tid&7)*8;
            *(uint4*)(DTg + chunk*8192 + (size_t)(v0+vv)*64 + c) = *(const uint4*)&DT[vv*72 + c];
        }
        if (havenext){
            if (tid < 128){
                int row = tid>>1, c8 = (tid&1)*8;
                *(uint4*)&UcS[nxt][row*16 + c8] = ucv;
            }
            if (tid<64) bvv[nxt][tid] = bvn;
        }
        __syncthreads();
        // S = e^{bC}*S + KpT @ DT^T   (2 tiles per wave: tm = wave*2+i)
        float lamC = __expf(bvv[cur][63]);
        #pragma unroll
        for (int i=0;i<2;i++){
            const int tm = wave*2 + i;
            f32x4 acc;
            #pragma unroll
            for (int r=0;r<4;r++) acc[r] = lamC * sreg[i][r];
            #pragma unroll
            for (int kk=0;kk<2;kk++)
                acc = __builtin_amdgcn_mfma_f32_16x16x32_bf16(
                    frag(KpT, tm*16+lr, 72, kk*32+lg*8),
                    frag(DT,  lr, 72, kk*32+lg*8), acc, 0,0,0);
            #pragma unroll
            for (int r=0;r<4;r++){
                int k = tm*16+lg*4+r;
                sreg[i][r] = acc[r];
                u16 hi = f2bf(acc[r]);
                STh[lr*136 + k] = hi;
                STl[lr*136 + k] = f2bf(acc[r] - bf2f(hi));
            }
        }
        __syncthreads();
    }
}

// ---------- o = o1 + QKmask @ Delta ----------
__global__ __launch_bounds__(256) void k_out(const u16* __restrict__ mixed,
        const float* __restrict__ barr, const float* __restrict__ o1g,
        const u16* __restrict__ DTg, float* __restrict__ o){
    __shared__ __align__(16) u16 Qs[64*128];
    __shared__ __align__(16) u16 Ks[64*128];
    __shared__ __align__(16) u16 DTs[128*64];
    __shared__ __align__(16) u16 QKm[64*72];
    __shared__ float bvv[64];
    const int tid = threadIdx.x, lane = tid&63, wave = tid>>6;
    const int lr = lane&15, lg = lane>>4;
    const int chunk = blockIdx.x;
    const int ci = chunk&63, bh = chunk>>6, b = bh>>4, h = bh&15;
    const size_t rowbase = (size_t)b*T_SEQ + ci*64;
    const u16* qg = mixed + rowbase*CONV_CH + h*128;
    const u16* kg = qg + KD;
    #pragma unroll
    for (int pass=0; pass<4; pass++){
        int row = pass*16 + (tid>>4), co = (tid&15)*8;
        gl_lds16(qg + (size_t)row*CONV_CH + co, Qs + row*128 + co);
        gl_lds16(kg + (size_t)row*CONV_CH + co, Ks + row*128 + co);
        gl_lds16(DTg + (size_t)chunk*8192 + pass*2048 + tid*8, DTs + pass*2048 + tid*8);
    }
    if (tid<64) bvv[tid] = barr[(size_t)chunk*64 + tid];
    __syncthreads();
    {
        f32x4 acc[4];
        #pragma unroll
        for (int tn=0; tn<4; tn++){
            f32x4 a = {};
            #pragma unroll
            for (int kk=0;kk<4;kk++)
                a = __builtin_amdgcn_mfma_f32_16x16x32_bf16(
                    frag(Qs, wave*16+lr, 128, kk*32+lg*8),
                    frag(Ks, tn*16+lr, 128, kk*32+lg*8), a, 0,0,0);
            acc[tn] = a;
        }
        #pragma unroll
        for (int tn=0;tn<4;tn++)
            #pragma unroll
            for (int r=0;r<4;r++){
                int t = wave*16+lg*4+r, s = tn*16+lr;
                float val = (t>=s) ? acc[tn][r]*__expf(bvv[t]-bvv[s]) : 0.f;
                QKm[t*72+s] = f2bf(val);
            }
    }
    __syncthreads();
    f32x4 acc[8] = {};
    #pragma unroll
    for (int kk=0;kk<2;kk++){
        bf16x8 af = frag(QKm, wave*16+lr, 72, kk*32+lg*8);
        #pragma unroll
        for (int tn=0;tn<8;tn++)
            acc[tn] = __builtin_amdgcn_mfma_f32_16x16x32_bf16(af, frag(DTs, tn*16+lr, 64, kk*32+lg*8), acc[tn], 0,0,0);
    }
    #pragma unroll
    for (int tn=0;tn<8;tn++)
        #pragma unroll
        for (int r=0;r<4;r++){
            int t = wave*16+lg*4+r, v = tn*16+lr;
            size_t idx = ((rowbase + t)*NH + h)*DKH + v;
            o[idx] = o1g[idx] + acc[tn][r];
        }
}

// ---------- x = RMSNorm(o * silu(z)) * norm_w, cast bf16 ----------
__global__ void k_gatenorm(const float* __restrict__ o, const u16* __restrict__ zbuf,
                           const float* __restrict__ norm_w, u16* __restrict__ x){
    int gw   = blockIdx.x*4 + (threadIdx.x>>6);
    int lane = threadIdx.x & 63;
    int bt = gw >> 4, h = gw & 15;
    const float* opr = o + ((size_t)bt*NH + h)*DKH + lane*2;
    const u16* zp = zbuf + (size_t)bt*VD + h*DKH + lane*2;
    float o0 = opr[0], o1 = opr[1];
    u32 zu = *(const u32*)zp;
    float z0 = bflo(zu), z1 = bfhi(zu);
    float x0 = o0 * (z0/(1.f+__expf(-z0)));
    float x1 = o1 * (z1/(1.f+__expf(-z1)));
    float ss = x0*x0 + x1*x1;
    #pragma unroll
    for (int m=1;m<64;m<<=1) ss += __shfl_xor(ss, m, 64);
    float sc = rsqrtf(ss*(1.f/128.f) + 1e-6f);
    x0 *= sc*norm_w[lane*2]; x1 *= sc*norm_w[lane*2+1];
    ((u32*)x)[(size_t)bt*(VD/2) + h*(DKH/2) + lane] = (u32)f2bf(x0) | ((u32)f2bf(x1)<<16);
}

extern "C" void kernel_launch(void* const* d_in, const int* in_sizes, int n_in,
                              void* d_out, int out_size, void* d_ws, size_t ws_size,
                              hipStream_t stream){
    (void)in_sizes; (void)n_in; (void)out_size; (void)ws_size;
    const float* hidden = (const float*)d_in[0];
    const float* W_qkvz = (const float*)d_in[1];
    const float* W_ba   = (const float*)d_in[2];
    const float* conv_w = (const float*)d_in[3];
    const float* conv_b = (const float*)d_in[4];
    const float* dt_bias= (const float*)d_in[5];
    const float* A_log  = (const float*)d_in[6];
    const float* norm_w = (const float*)d_in[7];
    const float* W_out  = (const float*)d_in[8];
    float* out = (float*)d_out;

    char* ws = (char*)d_ws;
    size_t off = 0;
    auto alloc = [&](size_t bytes)->char*{ char* p = ws + off; off += (bytes + 255) & ~(size_t)255; return p; };
    // Pool A (100.66 MB): h_bf|WqT -> Wcg|Ucg|DTg -> o|DTg
    char* poolA = alloc(100663296);
    u16*   h_bf = (u16*)poolA;
    u16*   WqT  = (u16*)(poolA + 50331648);
    u16*   Wcg  = (u16*)poolA;
    u16*   Ucg  = (u16*)(poolA + 33554432);
    u16*   DTg  = (u16*)(poolA + 67108864);
    float* o_b  = (float*)poolA;
    // Pool B (100.66 MB): qkv_lin -> o1g|barr -> x|barr
    char* poolB = alloc(100663296);
    u16*   qkv_lin = (u16*)poolB;
    float* o1g  = (float*)poolB;
    float* barr = (float*)(poolB + 67108864);
    u16*   x_b  = (u16*)poolB;
    u16*   WoT  = (u16*)  alloc((size_t)HID*VD*2);        // 12.6 MB
    u16*   zbuf = (u16*)  alloc((size_t)MROWS*VD*2);      // 33.55 MB
    u16*   mixed= (u16*)  alloc((size_t)MROWS*CONV_CH*2); // 100.66 MB
    float2* be_b= (float2*)alloc((size_t)MROWS*NH*8);     // 1.05 MB
    // total 349.2 MB == proven footprint

    k_cast<<<2048,256,0,stream>>>(hidden, h_bf, MROWS*HID/4);
    k_transpose_cast<<<(HID/32)*(N_QKVZ/32),256,0,stream>>>(W_qkvz, WqT, HID, N_QKVZ);
    k_transpose_cast<<<(VD/32)*(HID/32),256,0,stream>>>(W_out, WoT, VD, HID);
    k_gemm_bt<true><<<(MROWS/128)*(N_QKVZ/128),256,0,stream>>>(h_bf, WqT, qkv_lin, zbuf,
                         MROWS, N_QKVZ, HID, CONV_CH, CONV_CH, VD);
    k_ba<<<MROWS/8,256,0,stream>>>(hidden, W_ba, dt_bias, A_log, be_b);
    k_conv_silu<<<(MROWS/8)*24,256,0,stream>>>(qkv_lin, conv_w, conv_b, mixed);
    k_prep<<<2048,512,0,stream>>>(mixed, be_b, Wcg, Ucg, barr);
    k_seq<<<256,256,0,stream>>>(mixed, Wcg, Ucg, barr, o1g, DTg);
    k_out<<<2048,256,0,stream>>>(mixed, barr, o1g, DTg, o_b);
    k_gatenorm<<<MROWS*NH/4,256,0,stream>>>(o_b, zbuf, norm_w, x_b);
    k_gemm_bt<false><<<(MROWS/128)*(HID/128),256,0,stream>>>(x_b, WoT, out, nullptr,
                         MROWS, HID, VD, 1<<30, HID, 0);
}

// Round 12
// 1340.559 us; speedup vs baseline: 1.2371x; 1.0109x over previous
//
#include <hip/hip_runtime.h>
#include <cstdint>
#include <cstddef>

#define T_SEQ 4096
#define HID 3072
#define NH 16
#define DKH 128
#define KD 2048
#define VD 2048
#define N_QKVZ 8192
#define CONV_CH 6144
#define MROWS 8192  // B*T

typedef unsigned short u16;
typedef unsigned int u32;

typedef __attribute__((ext_vector_type(8))) short bf16x8;
typedef __attribute__((ext_vector_type(4))) float f32x4;

__device__ __forceinline__ float bf2f(u16 u){ u32 t=((u32)u)<<16; float f; __builtin_memcpy(&f,&t,4); return f; }
__device__ __forceinline__ float bflo(u32 u){ u32 t=u<<16; float f; __builtin_memcpy(&f,&t,4); return f; }
__device__ __forceinline__ float bfhi(u32 u){ u32 t=u&0xffff0000u; float f; __builtin_memcpy(&f,&t,4); return f; }
__device__ __forceinline__ u16 f2bf(float f){ u32 i; __builtin_memcpy(&i,&f,4); return (u16)((i + 0x7fffu + ((i>>16)&1u))>>16); }

__device__ __forceinline__ void gl_lds16(const u16* g, u16* l){
    __builtin_amdgcn_global_load_lds(
        (const __attribute__((address_space(1))) void*)g,
        (__attribute__((address_space(3))) void*)l, 16, 0, 0);
}

__device__ __forceinline__ bf16x8 frag(const u16* p, int row, int stride, int k0){
    return *(const bf16x8*)(p + (size_t)row*stride + k0);
}

// ---------- cast f32 -> bf16 (flat) ----------
__global__ void k_cast(const float* __restrict__ in, u16* __restrict__ out, int n4){
    int stride = gridDim.x*blockDim.x;
    for (int i = blockIdx.x*blockDim.x + threadIdx.x; i < n4; i += stride){
        float4 v = ((const float4*)in)[i];
        u32 lo = (u32)f2bf(v.x) | ((u32)f2bf(v.y)<<16);
        u32 hi = (u32)f2bf(v.z) | ((u32)f2bf(v.w)<<16);
        ((uint2*)out)[i] = make_uint2(lo,hi);
    }
}

// ---------- transpose + cast: in[R][C] f32 -> out[C][R] bf16 ----------
__global__ void k_transpose_cast(const float* __restrict__ in, u16* __restrict__ out, int R, int C){
    __shared__ u16 tile[32][33];
    int nbc = C >> 5;
    int bc = blockIdx.x % nbc, br = blockIdx.x / nbc;
    int c0 = bc<<5, r0 = br<<5;
    int tx = threadIdx.x & 31, ty = threadIdx.x >> 5;
    #pragma unroll
    for (int i=0;i<4;i++){
        int r = ty + i*8;
        tile[r][tx] = f2bf(in[(size_t)(r0+r)*C + c0 + tx]);
    }
    __syncthreads();
    #pragma unroll
    for (int i=0;i<4;i++){
        int r = ty + i*8;
        out[(size_t)(c0+r)*R + r0 + tx] = tile[tx][r];
    }
}

// ---------- bf16 MFMA GEMM, 128x128 tile, dbuf stage-first, grouped order, LDS epilogue ----------
template<bool OUT_BF16>
__global__ __launch_bounds__(256, 2) void k_gemm_bt(const u16* __restrict__ A, const u16* __restrict__ Bt,
                                                 void* __restrict__ C1, void* __restrict__ C2,
                                                 int M, int N, int K, int csplit, int ld1, int ld2){
    __shared__ __align__(16) u16 SM[4*128*64];   // 64 KB: As[2] | Bs[2]; reused as epilogue buffer
    u16 (*As)[128*64] = (u16(*)[128*64])SM;
    u16 (*Bs)[128*64] = (u16(*)[128*64])(SM + 2*128*64);
    const int tid  = threadIdx.x;
    const int lane = tid & 63;
    const int wave = tid >> 6;
    const int wm = (wave >> 1) << 6;
    const int wn = (wave & 1) << 6;
    const int lr = lane & 15, lg = lane >> 4;
    const int nbn = N >> 7;
    const int per = 8*nbn;
    const int grp = blockIdx.x / per, rem = blockIdx.x % per;
    const int bm = grp*8 + (rem & 7);
    const int bn = rem >> 3;
    f32x4 acc[4][4] = {};
    const size_t aRow0 = (size_t)bm*128;
    const size_t bRow0 = (size_t)bn*128;
    const int srow = wave*32 + (lane>>3);
    const int scol = (lane&7)*8;

    auto STAGE = [&](int kt, int b){
        const u16* ga = A  + (aRow0 + srow)*K + kt + scol;
        const u16* gb = Bt + (bRow0 + srow)*K + kt + scol;
        u16* la = &As[b][wave*2048];
        u16* lb = &Bs[b][wave*2048];
        #pragma unroll
        for (int i=0;i<4;i++){
            gl_lds16(ga + (size_t)i*8*K, la + i*512);
            gl_lds16(gb + (size_t)i*8*K, lb + i*512);
        }
    };

    STAGE(0, 0);
    __syncthreads();

    const int NT = K >> 6;
    int cur = 0;
    for (int t = 0; t < NT; t++){
        if (t+1 < NT) STAGE((t+1)*64, cur^1);
        #pragma unroll
        for (int kk=0; kk<2; kk++){
            bf16x8 af[4], bfv[4];
            #pragma unroll
            for (int i=0;i<4;i++){
                af[i]  = *(const bf16x8*)&As[cur][((wm + i*16 + lr)<<6) + (kk<<5) + (lg<<3)];
                bfv[i] = *(const bf16x8*)&Bs[cur][((wn + i*16 + lr)<<6) + (kk<<5) + (lg<<3)];
            }
            __builtin_amdgcn_s_setprio(1);
            #pragma unroll
            for (int i=0;i<4;i++)
                #pragma unroll
                for (int j=0;j<4;j++)
                    acc[i][j] = __builtin_amdgcn_mfma_f32_16x16x32_bf16(af[i], bfv[j], acc[i][j], 0, 0, 0);
            __builtin_amdgcn_s_setprio(0);
        }
        __syncthreads();
        cur ^= 1;
    }

    if (OUT_BF16){
        u16* Cs = SM;                       // 128*136*2 = 34816 B
        #pragma unroll
        for (int i=0;i<4;i++)
            #pragma unroll
            for (int j=0;j<4;j++)
                #pragma unroll
                for (int r=0;r<4;r++)
                    Cs[(wm + i*16 + lg*4 + r)*136 + wn + j*16 + lr] = f2bf(acc[i][j][r]);
        __syncthreads();
        int row = tid >> 1, half = tid & 1;
        int colbase = bn*128 + half*64;
        u16* dst; int ld;
        if (bn*128 < csplit){ dst = (u16*)C1; ld = ld1; }
        else { dst = (u16*)C2; ld = ld2; colbase -= csplit; }
        u16* gp = dst + (size_t)(bm*128+row)*ld + colbase;
        const u16* sp = Cs + row*136 + half*64;
        #pragma unroll
        for (int k2=0;k2<8;k2++) *(uint4*)(gp + k2*8) = *(const uint4*)(sp + k2*8);
    } else {
        #pragma unroll
        for (int i=0;i<4;i++)
            #pragma unroll
            for (int j=0;j<4;j++)
                #pragma unroll
                for (int r=0;r<4;r++){
                    int row = bm*128 + wm + i*16 + lg*4 + r;
                    int col = bn*128 + wn + j*16 + lr;
                    ((float*)C1)[(size_t)row*ld1 + col] = acc[i][j][r];
                }
    }
}

// ---------- ba = hidden @ W_ba ; be[].x = sigmoid(b), be[].y = g (log-decay) ----------
__global__ void k_ba(const float* __restrict__ hidden, const float* __restrict__ W_ba,
                     const float* __restrict__ dt_bias, const float* __restrict__ A_log,
                     float2* __restrict__ be){
    int row = blockIdx.x*8 + (threadIdx.x>>5);
    int col = threadIdx.x & 31;
    const float* h = hidden + (size_t)row*HID;
    float s0=0.f, s1=0.f, s2=0.f, s3=0.f;
    #pragma unroll 2
    for (int k=0;k<HID;k+=4){
        s0 = fmaf(h[k],   W_ba[(k)*32+col],   s0);
        s1 = fmaf(h[k+1], W_ba[(k+1)*32+col], s1);
        s2 = fmaf(h[k+2], W_ba[(k+2)*32+col], s2);
        s3 = fmaf(h[k+3], W_ba[(k+3)*32+col], s3);
    }
    float s = (s0+s1)+(s2+s3);
    if (col < NH){
        be[(size_t)row*NH + col].x = 1.f/(1.f+expf(-s));
    } else {
        int hh = col - NH;
        float x = s + dt_bias[hh];
        float sp = fmaxf(x,0.f) + log1pf(expf(-fabsf(x)));   // softplus, stable
        be[(size_t)row*NH + hh].y = -expf(A_log[hh])*sp;     // g (not exponentiated)
    }
}

// ---------- causal conv (KW=4) + bias + SiLU + fused q/k l2-norm ----------
// block = 8 consecutive t x 256 channels (rolling window; 1.375x read amp)
__global__ __launch_bounds__(256) void k_conv_silu(const u16* __restrict__ qkv, const float* __restrict__ conv_w,
                            const float* __restrict__ conv_b, u16* __restrict__ mixed){
    __shared__ float hsum[4][8];
    const int bid = blockIdx.x, tid = threadIdx.x;
    const int c0 = (bid % 24) << 8;
    const long bt0 = (long)(bid / 24) * 8;
    const int ts0 = (int)(bt0 % T_SEQ);          // multiple of 8
    const int c = c0 + tid;
    const u16* in = qkv + (size_t)bt0*CONV_CH + c;
    float4 w = *(const float4*)(conv_w + c*4);
    float bias = conv_b[c];
    float w0=0.f, w1=0.f, w2=0.f;
    if (ts0 > 0){
        w0 = bf2f(in[-3*CONV_CH]); w1 = bf2f(in[-2*CONV_CH]); w2 = bf2f(in[-1*CONV_CH]);
    }
    float sv[8];
    #pragma unroll
    for (int j=0;j<8;j++){
        float xc = bf2f(in[(ptrdiff_t)j*CONV_CH]);
        float acc = bias + w.x*w0 + w.y*w1 + w.z*w2 + w.w*xc;
        sv[j] = acc / (1.f + __expf(-acc));
        w0 = w1; w1 = w2; w2 = xc;
    }
    if (c0 < 2*KD){                               // q/k: fused l2-norm (block-uniform branch)
        float ss[8];
        #pragma unroll
        for (int j=0;j<8;j++) ss[j] = sv[j]*sv[j];
        #pragma unroll
        for (int m=1;m<64;m<<=1)
            #pragma unroll
            for (int j=0;j<8;j++) ss[j] += __shfl_xor(ss[j], m, 64);
        if ((tid&63)==0)
            #pragma unroll
            for (int j=0;j<8;j++) hsum[tid>>6][j] = ss[j];
        __syncthreads();
        int head = tid>>7;
        float qs = (c0 + head*128 < KD) ? 0.08838834764831845f : 1.f;
        #pragma unroll
        for (int j=0;j<8;j++){
            float tot = hsum[head*2][j] + hsum[head*2+1][j];
            sv[j] *= rsqrtf(tot + 1e-6f) * qs;
        }
    }
    u16* outp = mixed + (size_t)bt0*CONV_CH + c;
    #pragma unroll
    for (int j=0;j<8;j++) outp[(size_t)j*CONV_CH] = f2bf(sv[j]);
}

// ================= chunked delta rule =================
__global__ __launch_bounds__(512) void k_prep(const u16* __restrict__ mixed,
        const float2* __restrict__ be, u16* __restrict__ Wcg, u16* __restrict__ Ucg,
        float* __restrict__ barr){
    __shared__ __align__(16) u16 Ks[64*128];
    __shared__ __align__(16) u16 Vs[64*128];
    __shared__ float Am[64*64];
    __shared__ __align__(16) float RHS[64*256];
    __shared__ float bv[64], betav[64], lamv[64];
    const int tid = threadIdx.x;
    const int lane = tid & 63, wave = tid >> 6;
    const int lr = lane & 15, lg = lane >> 4;
    const int chunk = blockIdx.x;
    const int ci = chunk & 63, bh = chunk >> 6, b = bh >> 4, h = bh & 15;
    const size_t rowbase = (size_t)b*T_SEQ + ci*64;

    const u16* kg = mixed + rowbase*CONV_CH + KD + h*128;
    const u16* vg = mixed + rowbase*CONV_CH + 2*KD + h*128;
    #pragma unroll
    for (int pass=0; pass<2; pass++){
        int row = (tid>>4) + pass*32;
        int co = (tid&15)*8;
        gl_lds16(kg + (size_t)row*CONV_CH + co, Ks + row*128 + co);
        gl_lds16(vg + (size_t)row*CONV_CH + co, Vs + row*128 + co);
    }
    if (tid < 64){
        float2 bg = be[(rowbase + tid)*NH + h];
        float acc = bg.y;
        #pragma unroll
        for (int m=1;m<64;m<<=1){ float u = __shfl_up(acc, m, 64); if (tid >= m) acc += u; }
        bv[tid] = acc; betav[tid] = bg.x; lamv[tid] = __expf(acc);
        barr[(size_t)chunk*64 + tid] = acc;
    }
    __syncthreads();
    #pragma unroll
    for (int i=0;i<2;i++){
        int tile = wave*2 + i;
        int tm = tile>>2, tn = tile&3;
        f32x4 acc = {};
        #pragma unroll
        for (int kk=0;kk<4;kk++)
            acc = __builtin_amdgcn_mfma_f32_16x16x32_bf16(
                frag(Ks, tm*16+lr, 128, kk*32+lg*8),
                frag(Ks, tn*16+lr, 128, kk*32+lg*8), acc, 0,0,0);
        #pragma unroll
        for (int r=0;r<4;r++){
            int t = tm*16 + lg*4 + r, s = tn*16 + lr;
            Am[t*64+s] = (t>s) ? betav[t]*__expf(bv[t]-bv[s])*acc[r] : 0.f;
        }
    }
    __syncthreads();
    for (int i=tid; i<64*256; i+=512){
        int r = i>>8, j = i&255;
        RHS[i] = (j<128) ? betav[r]*lamv[r]*bf2f(Ks[r*128+j])
                         : betav[r]*bf2f(Vs[r*128 + (j-128)]);
    }
    __syncthreads();
    for (int blk=0; blk<8; blk++){
        int base = blk*8;
        if (base){
            int r = base + (tid>>6);
            int j0 = (tid&63)*4;
            float4 x = *(float4*)&RHS[r*256 + j0];
            for (int s=0; s<base; s++){
                float a = Am[r*64+s];
                float4 y = *(float4*)&RHS[s*256 + j0];
                x.x = fmaf(-a, y.x, x.x); x.y = fmaf(-a, y.y, x.y);
                x.z = fmaf(-a, y.z, x.z); x.w = fmaf(-a, y.w, x.w);
            }
            *(float4*)&RHS[r*256 + j0] = x;
        }
        __syncthreads();
        if (tid < 256){
            float x[8];
            #pragma unroll
            for (int i=0;i<8;i++) x[i] = RHS[(base+i)*256 + tid];
            #pragma unroll
            for (int r=1;r<8;r++)
                #pragma unroll
                for (int s=0;s<r;s++)
                    x[r] = fmaf(-Am[(base+r)*64 + base+s], x[s], x[r]);
            #pragma unroll
            for (int i=1;i<8;i++) RHS[(base+i)*256 + tid] = x[i];
        }
        __syncthreads();
    }
    for (int i=tid; i<8192; i+=512){
        int r = i>>7, c = i&127;
        Wcg[(size_t)chunk*8192 + i] = f2bf(RHS[r*256 + c]);
        Ucg[(size_t)chunk*8192 + i] = f2bf(RHS[r*256 + 128 + c]);
    }
}

// ---------- sequential chunk recurrence + fused o1 = diag(e^b) Q @ S0 ----------
// grid 256: blk = vs*32 + bh, 8 v-splits of 16 columns each; S in registers.
__global__ __launch_bounds__(256) void k_seq(const u16* __restrict__ mixed,
        const u16* __restrict__ Wcg, const u16* __restrict__ Ucg,
        const float* __restrict__ barr,
        float* __restrict__ o1g, u16* __restrict__ DTg){
    __shared__ __align__(16) u16 WcS[2][64*128];
    __shared__ __align__(16) u16 Ks[2][64*128];
    __shared__ __align__(16) u16 Qs[2][64*128];
    __shared__ __align__(16) u16 UcS[2][64*16];
    __shared__ __align__(16) u16 KpT[128*72];
    __shared__ __align__(16) u16 DT[16*72];
    __shared__ __align__(16) u16 STh[16*136];
    __shared__ __align__(16) u16 STl[16*136];
    __shared__ float bvv[2][64], esc[64];
    const int tid = threadIdx.x, lane = tid&63, wave = tid>>6;
    const int lr = lane&15, lg = lane>>4;
    const int blk = blockIdx.x;
    const int bh = blk & 31, vs = blk >> 5;       // vs 0..7
    const int b = bh>>4, h = bh&15, v0 = vs*16;
    const u16* qgb = mixed + (size_t)b*T_SEQ*CONV_CH + h*128;
    const u16* kgb = qgb + KD;

    float sreg[2][4];
    #pragma unroll
    for (int i=0;i<2;i++)
        #pragma unroll
        for (int r=0;r<4;r++) sreg[i][r] = 0.f;
    for (int i=tid; i<16*136; i+=256){ STh[i]=0; STl[i]=0; }

    auto STAGE = [&](int ci2, int bf){
        const size_t ch = (size_t)(bh*64 + ci2);
        #pragma unroll
        for (int pass=0; pass<4; pass++){
            gl_lds16(Wcg + ch*8192 + pass*2048 + tid*8, &WcS[bf][pass*2048 + tid*8]);
            int row = pass*16 + (tid>>4), co = (tid&15)*8;
            gl_lds16(kgb + ((size_t)(ci2*64) + row)*CONV_CH + co, &Ks[bf][row*128 + co]);
            gl_lds16(qgb + ((size_t)(ci2*64) + row)*CONV_CH + co, &Qs[bf][row*128 + co]);
        }
    };

    STAGE(0, 0);
    if (tid < 128){
        int row = tid>>1, c8 = (tid&1)*8;
        *(uint4*)&UcS[0][row*16 + c8] = *(const uint4*)(Ucg + (size_t)(bh*64)*8192 + (size_t)row*128 + v0 + c8);
    }
    if (tid<64) bvv[0][tid] = barr[(size_t)(bh*64)*64 + tid];
    __syncthreads();

    for (int ci=0; ci<64; ci++){
        const int cur = ci&1, nxt = cur^1;
        const size_t chunk = (size_t)(bh*64 + ci);
        const size_t rowbase = (size_t)b*T_SEQ + ci*64;
        uint4 ucv = {0,0,0,0}; float bvn = 0.f;
        const bool havenext = (ci+1 < 64);
        if (havenext){
            STAGE(ci+1, nxt);
            if (tid < 128)
                ucv = *(const uint4*)(Ucg + (chunk+1)*8192 + (size_t)(tid>>1)*128 + v0 + (tid&1)*8);
            if (tid<64) bvn = barr[(chunk+1)*64 + tid];
        }
        if (tid<64) esc[tid] = __expf(bvv[cur][63] - bvv[cur][tid]);
        // Delta = Uc - Wc@S0 -> DT [v][t]  (1 tile per wave: tm=wave, tn=0)
        {
            const int tm = wave;
            f32x4 acc = {};
            #pragma unroll
            for (int kk=0;kk<4;kk++){
                bf16x8 af = frag(WcS[cur], tm*16+lr, 128, kk*32+lg*8);
                acc = __builtin_amdgcn_mfma_f32_16x16x32_bf16(af, frag(STh, lr, 136, kk*32+lg*8), acc, 0,0,0);
                acc = __builtin_amdgcn_mfma_f32_16x16x32_bf16(af, frag(STl, lr, 136, kk*32+lg*8), acc, 0,0,0);
            }
            #pragma unroll
            for (int r=0;r<4;r++){
                int t = tm*16+lg*4+r;
                DT[lr*72 + t] = f2bf(bf2f(UcS[cur][t*16+lr]) - acc[r]);
            }
        }
        // o1 = e^{b_t} * (Q @ S0)  (1 tile per wave)
        {
            const int tm = wave;
            f32x4 acc = {};
            #pragma unroll
            for (int kk=0;kk<4;kk++){
                bf16x8 af = frag(Qs[cur], tm*16+lr, 128, kk*32+lg*8);
                acc = __builtin_amdgcn_mfma_f32_16x16x32_bf16(af, frag(STh, lr, 136, kk*32+lg*8), acc, 0,0,0);
                acc = __builtin_amdgcn_mfma_f32_16x16x32_bf16(af, frag(STl, lr, 136, kk*32+lg*8), acc, 0,0,0);
            }
            #pragma unroll
            for (int r=0;r<4;r++){
                int t = tm*16+lg*4+r;
                o1g[((rowbase + t)*NH + h)*DKH + v0 + lr] = acc[r]*__expf(bvv[cur][t]);
            }
        }
        __syncthreads();
        // KpT[k][t] = K[t][k]*esc[t]  (u32-packed writes: 16 iterations)
        for (int i=tid; i<4096; i+=256){
            int k = i & 127, t = (i >> 7) * 2;
            u32 pack = (u32)f2bf(bf2f(Ks[cur][t*128 + k]) * esc[t])
                     | ((u32)f2bf(bf2f(Ks[cur][(t+1)*128 + k]) * esc[t+1]) << 16);
            *(u32*)&KpT[(size_t)k*72 + t] = pack;
        }
        if (tid < 128){
            int vv = tid>>3, c = (tid&7)*8;
            *(uint4*)(DTg + chunk*8192 + (size_t)(v0+vv)*64 + c) = *(const uint4*)&DT[vv*72 + c];
        }
        if (havenext){
            if (tid < 128){
                int row = tid>>1, c8 = (tid&1)*8;
                *(uint4*)&UcS[nxt][row*16 + c8] = ucv;
            }
            if (tid<64) bvv[nxt][tid] = bvn;
        }
        __syncthreads();
        // S = e^{bC}*S + KpT @ DT^T   (2 tiles per wave: tm = wave*2+i)
        float lamC = __expf(bvv[cur][63]);
        #pragma unroll
        for (int i=0;i<2;i++){
            const int tm = wave*2 + i;
            f32x4 acc;
            #pragma unroll
            for (int r=0;r<4;r++) acc[r] = lamC * sreg[i][r];
            #pragma unroll
            for (int kk=0;kk<2;kk++)
                acc = __builtin_amdgcn_mfma_f32_16x16x32_bf16(
                    frag(KpT, tm*16+lr, 72, kk*32+lg*8),
                    frag(DT,  lr, 72, kk*32+lg*8), acc, 0,0,0);
            #pragma unroll
            for (int r=0;r<4;r++){
                int k = tm*16+lg*4+r;
                sreg[i][r] = acc[r];
                u16 hi = f2bf(acc[r]);
                STh[lr*136 + k] = hi;
                STl[lr*136 + k] = f2bf(acc[r] - bf2f(hi));
            }
        }
        __syncthreads();
    }
}

// ---------- o = o1 + QKmask @ Delta ; fused gate+RMSNorm -> x written in-place into zbuf ----------
__global__ __launch_bounds__(256) void k_out(const u16* __restrict__ mixed,
        const float* __restrict__ barr, const float* __restrict__ o1g,
        const u16* __restrict__ DTg, u16* __restrict__ zio,
        const float* __restrict__ norm_w){
    __shared__ __align__(16) u16 Qs[64*128];
    __shared__ __align__(16) u16 Ks[64*128];
    __shared__ __align__(16) u16 DTs[128*64];
    __shared__ __align__(16) u16 QKm[64*72];
    __shared__ float bvv[64];
    __shared__ float nw[128];
    const int tid = threadIdx.x, lane = tid&63, wave = tid>>6;
    const int lr = lane&15, lg = lane>>4;
    const int chunk = blockIdx.x;
    const int ci = chunk&63, bh = chunk>>6, b = bh>>4, h = bh&15;
    const size_t rowbase = (size_t)b*T_SEQ + ci*64;
    const u16* qg = mixed + rowbase*CONV_CH + h*128;
    const u16* kg = qg + KD;
    #pragma unroll
    for (int pass=0; pass<4; pass++){
        int row = pass*16 + (tid>>4), co = (tid&15)*8;
        gl_lds16(qg + (size_t)row*CONV_CH + co, Qs + row*128 + co);
        gl_lds16(kg + (size_t)row*CONV_CH + co, Ks + row*128 + co);
        gl_lds16(DTg + (size_t)chunk*8192 + pass*2048 + tid*8, DTs + pass*2048 + tid*8);
    }
    if (tid<64) bvv[tid] = barr[(size_t)chunk*64 + tid];
    if (tid<128) nw[tid] = norm_w[tid];
    __syncthreads();
    {
        f32x4 acc[4];
        #pragma unroll
        for (int tn=0; tn<4; tn++){
            f32x4 a = {};
            #pragma unroll
            for (int kk=0;kk<4;kk++)
                a = __builtin_amdgcn_mfma_f32_16x16x32_bf16(
                    frag(Qs, wave*16+lr, 128, kk*32+lg*8),
                    frag(Ks, tn*16+lr, 128, kk*32+lg*8), a, 0,0,0);
            acc[tn] = a;
        }
        #pragma unroll
        for (int tn=0;tn<4;tn++)
            #pragma unroll
            for (int r=0;r<4;r++){
                int t = wave*16+lg*4+r, s = tn*16+lr;
                float val = (t>=s) ? acc[tn][r]*__expf(bvv[t]-bvv[s]) : 0.f;
                QKm[t*72+s] = f2bf(val);
            }
    }
    __syncthreads();
    f32x4 acc[8] = {};
    #pragma unroll
    for (int kk=0;kk<2;kk++){
        bf16x8 af = frag(QKm, wave*16+lr, 72, kk*32+lg*8);
        #pragma unroll
        for (int tn=0;tn<8;tn++)
            acc[tn] = __builtin_amdgcn_mfma_f32_16x16x32_bf16(af, frag(DTs, tn*16+lr, 64, kk*32+lg*8), acc[tn], 0,0,0);
    }
    // fused epilogue: x = RMSNorm((o1 + QKm@Delta) * silu(z)) * norm_w, overwrite z tile in place.
    // Each lane reads exactly the (t,v) elements it later writes -> race-free, deterministic.
    float xv[8][4];
    float ss[4] = {0.f,0.f,0.f,0.f};
    #pragma unroll
    for (int tn=0;tn<8;tn++)
        #pragma unroll
        for (int r=0;r<4;r++){
            int t = wave*16+lg*4+r, v = tn*16+lr;
            size_t bt = rowbase + t;
            float ov = o1g[(bt*NH + h)*DKH + v] + acc[tn][r];
            float z  = bf2f(zio[bt*VD + h*DKH + v]);
            float xx = ov * (z/(1.f+__expf(-z)));
            xv[tn][r] = xx;
            ss[r] = fmaf(xx, xx, ss[r]);
        }
    #pragma unroll
    for (int m=1;m<16;m<<=1)
        #pragma unroll
        for (int r=0;r<4;r++) ss[r] += __shfl_xor(ss[r], m, 64);
    float sc[4];
    #pragma unroll
    for (int r=0;r<4;r++) sc[r] = rsqrtf(ss[r]*(1.f/128.f) + 1e-6f);
    #pragma unroll
    for (int tn=0;tn<8;tn++)
        #pragma unroll
        for (int r=0;r<4;r++){
            int t = wave*16+lg*4+r, v = tn*16+lr;
            zio[(rowbase + t)*VD + h*DKH + v] = f2bf(xv[tn][r]*sc[r]*nw[v]);
        }
}

extern "C" void kernel_launch(void* const* d_in, const int* in_sizes, int n_in,
                              void* d_out, int out_size, void* d_ws, size_t ws_size,
                              hipStream_t stream){
    (void)in_sizes; (void)n_in; (void)out_size; (void)ws_size;
    const float* hidden = (const float*)d_in[0];
    const float* W_qkvz = (const float*)d_in[1];
    const float* W_ba   = (const float*)d_in[2];
    const float* conv_w = (const float*)d_in[3];
    const float* conv_b = (const float*)d_in[4];
    const float* dt_bias= (const float*)d_in[5];
    const float* A_log  = (const float*)d_in[6];
    const float* norm_w = (const float*)d_in[7];
    const float* W_out  = (const float*)d_in[8];
    float* out = (float*)d_out;

    char* ws = (char*)d_ws;
    size_t off = 0;
    auto alloc = [&](size_t bytes)->char*{ char* p = ws + off; off += (bytes + 255) & ~(size_t)255; return p; };
    // Pool A (100.66 MB): h_bf|WqT -> Wcg|Ucg|DTg
    char* poolA = alloc(100663296);
    u16*   h_bf = (u16*)poolA;
    u16*   WqT  = (u16*)(poolA + 50331648);
    u16*   Wcg  = (u16*)poolA;
    u16*   Ucg  = (u16*)(poolA + 33554432);
    u16*   DTg  = (u16*)(poolA + 67108864);
    // Pool B (100.66 MB): qkv_lin -> o1g|barr
    char* poolB = alloc(100663296);
    u16*   qkv_lin = (u16*)poolB;
    float* o1g  = (float*)poolB;
    float* barr = (float*)(poolB + 67108864);
    u16*   WoT  = (u16*)  alloc((size_t)HID*VD*2);        // 12.6 MB
    u16*   zbuf = (u16*)  alloc((size_t)MROWS*VD*2);      // 33.55 MB (z -> x in place)
    u16*   mixed= (u16*)  alloc((size_t)MROWS*CONV_CH*2); // 100.66 MB
    float2* be_b= (float2*)alloc((size_t)MROWS*NH*8);     // 1.05 MB
    // total 349.2 MB == proven footprint

    k_cast<<<2048,256,0,stream>>>(hidden, h_bf, MROWS*HID/4);
    k_transpose_cast<<<(HID/32)*(N_QKVZ/32),256,0,stream>>>(W_qkvz, WqT, HID, N_QKVZ);
    k_transpose_cast<<<(VD/32)*(HID/32),256,0,stream>>>(W_out, WoT, VD, HID);
    k_gemm_bt<true><<<(MROWS/128)*(N_QKVZ/128),256,0,stream>>>(h_bf, WqT, qkv_lin, zbuf,
                         MROWS, N_QKVZ, HID, CONV_CH, CONV_CH, VD);
    k_ba<<<MROWS/8,256,0,stream>>>(hidden, W_ba, dt_bias, A_log, be_b);
    k_conv_silu<<<(MROWS/8)*24,256,0,stream>>>(qkv_lin, conv_w, conv_b, mixed);
    k_prep<<<2048,512,0,stream>>>(mixed, be_b, Wcg, Ucg, barr);
    k_seq<<<256,256,0,stream>>>(mixed, Wcg, Ucg, barr, o1g, DTg);
    k_out<<<2048,256,0,stream>>>(mixed, barr, o1g, DTg, zbuf, norm_w);
    k_gemm_bt<false><<<(MROWS/128)*(HID/128),256,0,stream>>>(zbuf, WoT, out, nullptr,
                         MROWS, HID, VD, 1<<30, HID, 0);
}

// Round 15
// 1338.377 us; speedup vs baseline: 1.2392x; 1.0016x over previous
//
#include <hip/hip_runtime.h>
#include <cstdint>
#include <cstddef>

#define T_SEQ 4096
#define HID 3072
#define NH 16
#define DKH 128
#define KD 2048
#define VD 2048
#define N_QKVZ 8192
#define CONV_CH 6144
#define MROWS 8192  // B*T

typedef unsigned short u16;
typedef unsigned int u32;

typedef __attribute__((ext_vector_type(8))) short bf16x8;
typedef __attribute__((ext_vector_type(4))) float f32x4;

__device__ __forceinline__ float bf2f(u16 u){ u32 t=((u32)u)<<16; float f; __builtin_memcpy(&f,&t,4); return f; }
__device__ __forceinline__ float bflo(u32 u){ u32 t=u<<16; float f; __builtin_memcpy(&f,&t,4); return f; }
__device__ __forceinline__ float bfhi(u32 u){ u32 t=u&0xffff0000u; float f; __builtin_memcpy(&f,&t,4); return f; }
__device__ __forceinline__ u16 f2bf(float f){ u32 i; __builtin_memcpy(&i,&f,4); return (u16)((i + 0x7fffu + ((i>>16)&1u))>>16); }

__device__ __forceinline__ void gl_lds16(const u16* g, u16* l){
    __builtin_amdgcn_global_load_lds(
        (const __attribute__((address_space(1))) void*)g,
        (__attribute__((address_space(3))) void*)l, 16, 0, 0);
}

__device__ __forceinline__ bf16x8 frag(const u16* p, int row, int stride, int k0){
    return *(const bf16x8*)(p + (size_t)row*stride + k0);
}

// ---------- cast f32 -> bf16 (flat) ----------
__global__ void k_cast(const float* __restrict__ in, u16* __restrict__ out, int n4){
    int stride = gridDim.x*blockDim.x;
    for (int i = blockIdx.x*blockDim.x + threadIdx.x; i < n4; i += stride){
        float4 v = ((const float4*)in)[i];
        u32 lo = (u32)f2bf(v.x) | ((u32)f2bf(v.y)<<16);
        u32 hi = (u32)f2bf(v.z) | ((u32)f2bf(v.w)<<16);
        ((uint2*)out)[i] = make_uint2(lo,hi);
    }
}

// ---------- transpose + cast: in[R][C] f32 -> out[C][R] bf16 ----------
__global__ void k_transpose_cast(const float* __restrict__ in, u16* __restrict__ out, int R, int C){
    __shared__ u16 tile[32][33];
    int nbc = C >> 5;
    int bc = blockIdx.x % nbc, br = blockIdx.x / nbc;
    int c0 = bc<<5, r0 = br<<5;
    int tx = threadIdx.x & 31, ty = threadIdx.x >> 5;
    #pragma unroll
    for (int i=0;i<4;i++){
        int r = ty + i*8;
        tile[r][tx] = f2bf(in[(size_t)(r0+r)*C + c0 + tx]);
    }
    __syncthreads();
    #pragma unroll
    for (int i=0;i<4;i++){
        int r = ty + i*8;
        out[(size_t)(c0+r)*R + r0 + tx] = tile[tx][r];
    }
}

// ---------- bf16 MFMA GEMM, 128x128 tile, dbuf stage-first, grouped order, LDS epilogue ----------
template<bool OUT_BF16>
__global__ __launch_bounds__(256, 2) void k_gemm_bt(const u16* __restrict__ A, const u16* __restrict__ Bt,
                                                 void* __restrict__ C1, void* __restrict__ C2,
                                                 int M, int N, int K, int csplit, int ld1, int ld2){
    __shared__ __align__(16) u16 SM[4*128*64];   // 64 KB: As[2] | Bs[2]; reused as epilogue buffer
    u16 (*As)[128*64] = (u16(*)[128*64])SM;
    u16 (*Bs)[128*64] = (u16(*)[128*64])(SM + 2*128*64);
    const int tid  = threadIdx.x;
    const int lane = tid & 63;
    const int wave = tid >> 6;
    const int wm = (wave >> 1) << 6;
    const int wn = (wave & 1) << 6;
    const int lr = lane & 15, lg = lane >> 4;
    const int nbn = N >> 7;
    const int per = 8*nbn;
    const int grp = blockIdx.x / per, rem = blockIdx.x % per;
    const int bm = grp*8 + (rem & 7);
    const int bn = rem >> 3;
    f32x4 acc[4][4] = {};
    const size_t aRow0 = (size_t)bm*128;
    const size_t bRow0 = (size_t)bn*128;
    const int srow = wave*32 + (lane>>3);
    const int scol = (lane&7)*8;

    auto STAGE = [&](int kt, int b){
        const u16* ga = A  + (aRow0 + srow)*K + kt + scol;
        const u16* gb = Bt + (bRow0 + srow)*K + kt + scol;
        u16* la = &As[b][wave*2048];
        u16* lb = &Bs[b][wave*2048];
        #pragma unroll
        for (int i=0;i<4;i++){
            gl_lds16(ga + (size_t)i*8*K, la + i*512);
            gl_lds16(gb + (size_t)i*8*K, lb + i*512);
        }
    };

    STAGE(0, 0);
    __syncthreads();

    const int NT = K >> 6;
    int cur = 0;
    for (int t = 0; t < NT; t++){
        if (t+1 < NT) STAGE((t+1)*64, cur^1);
        #pragma unroll
        for (int kk=0; kk<2; kk++){
            bf16x8 af[4], bfv[4];
            #pragma unroll
            for (int i=0;i<4;i++){
                af[i]  = *(const bf16x8*)&As[cur][((wm + i*16 + lr)<<6) + (kk<<5) + (lg<<3)];
                bfv[i] = *(const bf16x8*)&Bs[cur][((wn + i*16 + lr)<<6) + (kk<<5) + (lg<<3)];
            }
            __builtin_amdgcn_s_setprio(1);
            #pragma unroll
            for (int i=0;i<4;i++)
                #pragma unroll
                for (int j=0;j<4;j++)
                    acc[i][j] = __builtin_amdgcn_mfma_f32_16x16x32_bf16(af[i], bfv[j], acc[i][j], 0, 0, 0);
            __builtin_amdgcn_s_setprio(0);
        }
        __syncthreads();
        cur ^= 1;
    }

    if (OUT_BF16){
        u16* Cs = SM;                       // 128*136*2 = 34816 B
        #pragma unroll
        for (int i=0;i<4;i++)
            #pragma unroll
            for (int j=0;j<4;j++)
                #pragma unroll
                for (int r=0;r<4;r++)
                    Cs[(wm + i*16 + lg*4 + r)*136 + wn + j*16 + lr] = f2bf(acc[i][j][r]);
        __syncthreads();
        int row = tid >> 1, half = tid & 1;
        int colbase = bn*128 + half*64;
        u16* dst; int ld;
        if (bn*128 < csplit){ dst = (u16*)C1; ld = ld1; }
        else { dst = (u16*)C2; ld = ld2; colbase -= csplit; }
        u16* gp = dst + (size_t)(bm*128+row)*ld + colbase;
        const u16* sp = Cs + row*136 + half*64;
        #pragma unroll
        for (int k2=0;k2<8;k2++) *(uint4*)(gp + k2*8) = *(const uint4*)(sp + k2*8);
    } else {
        #pragma unroll
        for (int i=0;i<4;i++)
            #pragma unroll
            for (int j=0;j<4;j++)
                #pragma unroll
                for (int r=0;r<4;r++){
                    int row = bm*128 + wm + i*16 + lg*4 + r;
                    int col = bn*128 + wn + j*16 + lr;
                    ((float*)C1)[(size_t)row*ld1 + col] = acc[i][j][r];
                }
    }
}

// ---------- ba = hidden @ W_ba ; be[].x = sigmoid(b), be[].y = g (log-decay) ----------
__global__ void k_ba(const float* __restrict__ hidden, const float* __restrict__ W_ba,
                     const float* __restrict__ dt_bias, const float* __restrict__ A_log,
                     float2* __restrict__ be){
    int row = blockIdx.x*8 + (threadIdx.x>>5);
    int col = threadIdx.x & 31;
    const float* h = hidden + (size_t)row*HID;
    float s0=0.f, s1=0.f, s2=0.f, s3=0.f;
    #pragma unroll 2
    for (int k=0;k<HID;k+=4){
        s0 = fmaf(h[k],   W_ba[(k)*32+col],   s0);
        s1 = fmaf(h[k+1], W_ba[(k+1)*32+col], s1);
        s2 = fmaf(h[k+2], W_ba[(k+2)*32+col], s2);
        s3 = fmaf(h[k+3], W_ba[(k+3)*32+col], s3);
    }
    float s = (s0+s1)+(s2+s3);
    if (col < NH){
        be[(size_t)row*NH + col].x = 1.f/(1.f+expf(-s));
    } else {
        int hh = col - NH;
        float x = s + dt_bias[hh];
        float sp = fmaxf(x,0.f) + log1pf(expf(-fabsf(x)));   // softplus, stable
        be[(size_t)row*NH + hh].y = -expf(A_log[hh])*sp;     // g (not exponentiated)
    }
}

// ---------- causal conv (KW=4) + bias + SiLU + fused q/k l2-norm ----------
// block = 8 consecutive t x 256 channels (rolling window; 1.375x read amp)
__global__ __launch_bounds__(256) void k_conv_silu(const u16* __restrict__ qkv, const float* __restrict__ conv_w,
                            const float* __restrict__ conv_b, u16* __restrict__ mixed){
    __shared__ float hsum[4][8];
    const int bid = blockIdx.x, tid = threadIdx.x;
    const int c0 = (bid % 24) << 8;
    const long bt0 = (long)(bid / 24) * 8;
    const int ts0 = (int)(bt0 % T_SEQ);          // multiple of 8
    const int c = c0 + tid;
    const u16* in = qkv + (size_t)bt0*CONV_CH + c;
    float4 w = *(const float4*)(conv_w + c*4);
    float bias = conv_b[c];
    float w0=0.f, w1=0.f, w2=0.f;
    if (ts0 > 0){
        w0 = bf2f(in[-3*CONV_CH]); w1 = bf2f(in[-2*CONV_CH]); w2 = bf2f(in[-1*CONV_CH]);
    }
    float sv[8];
    #pragma unroll
    for (int j=0;j<8;j++){
        float xc = bf2f(in[(ptrdiff_t)j*CONV_CH]);
        float acc = bias + w.x*w0 + w.y*w1 + w.z*w2 + w.w*xc;
        sv[j] = acc / (1.f + __expf(-acc));
        w0 = w1; w1 = w2; w2 = xc;
    }
    if (c0 < 2*KD){                               // q/k: fused l2-norm (block-uniform branch)
        float ss[8];
        #pragma unroll
        for (int j=0;j<8;j++) ss[j] = sv[j]*sv[j];
        #pragma unroll
        for (int m=1;m<64;m<<=1)
            #pragma unroll
            for (int j=0;j<8;j++) ss[j] += __shfl_xor(ss[j], m, 64);
        if ((tid&63)==0)
            #pragma unroll
            for (int j=0;j<8;j++) hsum[tid>>6][j] = ss[j];
        __syncthreads();
        int head = tid>>7;
        float qs = (c0 + head*128 < KD) ? 0.08838834764831845f : 1.f;
        #pragma unroll
        for (int j=0;j<8;j++){
            float tot = hsum[head*2][j] + hsum[head*2+1][j];
            sv[j] *= rsqrtf(tot + 1e-6f) * qs;
        }
    }
    u16* outp = mixed + (size_t)bt0*CONV_CH + c;
    #pragma unroll
    for (int j=0;j<8;j++) outp[(size_t)j*CONV_CH] = f2bf(sv[j]);
}

// ================= chunked delta rule =================
__global__ __launch_bounds__(512) void k_prep(const u16* __restrict__ mixed,
        const float2* __restrict__ be, u16* __restrict__ Wcg, u16* __restrict__ Ucg,
        float* __restrict__ barr){
    __shared__ __align__(16) u16 Ks[64*128];
    __shared__ __align__(16) u16 Vs[64*128];
    __shared__ float Am[64*64];
    __shared__ __align__(16) float RHS[64*256];
    __shared__ float bv[64], betav[64], lamv[64];
    const int tid = threadIdx.x;
    const int lane = tid & 63, wave = tid >> 6;
    const int lr = lane & 15, lg = lane >> 4;
    const int chunk = blockIdx.x;
    const int ci = chunk & 63, bh = chunk >> 6, b = bh >> 4, h = bh & 15;
    const size_t rowbase = (size_t)b*T_SEQ + ci*64;

    const u16* kg = mixed + rowbase*CONV_CH + KD + h*128;
    const u16* vg = mixed + rowbase*CONV_CH + 2*KD + h*128;
    #pragma unroll
    for (int pass=0; pass<2; pass++){
        int row = (tid>>4) + pass*32;
        int co = (tid&15)*8;
        gl_lds16(kg + (size_t)row*CONV_CH + co, Ks + row*128 + co);
        gl_lds16(vg + (size_t)row*CONV_CH + co, Vs + row*128 + co);
    }
    if (tid < 64){
        float2 bg = be[(rowbase + tid)*NH + h];
        float acc = bg.y;
        #pragma unroll
        for (int m=1;m<64;m<<=1){ float u = __shfl_up(acc, m, 64); if (tid >= m) acc += u; }
        bv[tid] = acc; betav[tid] = bg.x; lamv[tid] = __expf(acc);
        barr[(size_t)chunk*64 + tid] = acc;
    }
    __syncthreads();
    #pragma unroll
    for (int i=0;i<2;i++){
        int tile = wave*2 + i;
        int tm = tile>>2, tn = tile&3;
        f32x4 acc = {};
        #pragma unroll
        for (int kk=0;kk<4;kk++)
            acc = __builtin_amdgcn_mfma_f32_16x16x32_bf16(
                frag(Ks, tm*16+lr, 128, kk*32+lg*8),
                frag(Ks, tn*16+lr, 128, kk*32+lg*8), acc, 0,0,0);
        #pragma unroll
        for (int r=0;r<4;r++){
            int t = tm*16 + lg*4 + r, s = tn*16 + lr;
            Am[t*64+s] = (t>s) ? betav[t]*__expf(bv[t]-bv[s])*acc[r] : 0.f;
        }
    }
    __syncthreads();
    for (int i=tid; i<64*256; i+=512){
        int r = i>>8, j = i&255;
        RHS[i] = (j<128) ? betav[r]*lamv[r]*bf2f(Ks[r*128+j])
                         : betav[r]*bf2f(Vs[r*128 + (j-128)]);
    }
    __syncthreads();
    for (int blk=0; blk<8; blk++){
        int base = blk*8;
        if (base){
            int r = base + (tid>>6);
            int j0 = (tid&63)*4;
            float4 x = *(float4*)&RHS[r*256 + j0];
            for (int s=0; s<base; s++){
                float a = Am[r*64+s];
                float4 y = *(float4*)&RHS[s*256 + j0];
                x.x = fmaf(-a, y.x, x.x); x.y = fmaf(-a, y.y, x.y);
                x.z = fmaf(-a, y.z, x.z); x.w = fmaf(-a, y.w, x.w);
            }
            *(float4*)&RHS[r*256 + j0] = x;
        }
        __syncthreads();
        if (tid < 256){
            float x[8];
            #pragma unroll
            for (int i=0;i<8;i++) x[i] = RHS[(base+i)*256 + tid];
            #pragma unroll
            for (int r=1;r<8;r++)
                #pragma unroll
                for (int s=0;s<r;s++)
                    x[r] = fmaf(-Am[(base+r)*64 + base+s], x[s], x[r]);
            #pragma unroll
            for (int i=1;i<8;i++) RHS[(base+i)*256 + tid] = x[i];
        }
        __syncthreads();
    }
    for (int i=tid; i<8192; i+=512){
        int r = i>>7, c = i&127;
        Wcg[(size_t)chunk*8192 + i] = f2bf(RHS[r*256 + c]);
        Ucg[(size_t)chunk*8192 + i] = f2bf(RHS[r*256 + 128 + c]);
    }
}

// ---------- sequential chunk recurrence + fused o1 = diag(e^b) Q @ S0 ----------
// grid 256: blk = vs*32 + bh, 8 v-splits of 16 columns each; S in registers.
__global__ __launch_bounds__(256) void k_seq(const u16* __restrict__ mixed,
        const u16* __restrict__ Wcg, const u16* __restrict__ Ucg,
        const float* __restrict__ barr,
        float* __restrict__ o1g, u16* __restrict__ DTg){
    __shared__ __align__(16) u16 WcS[2][64*128];
    __shared__ __align__(16) u16 Ks[2][64*128];
    __shared__ __align__(16) u16 Qs[2][64*128];
    __shared__ __align__(16) u16 UcS[2][64*16];
    __shared__ __align__(16) u16 KpT[128*72];
    __shared__ __align__(16) u16 DT[16*72];
    __shared__ __align__(16) u16 STh[16*136];
    __shared__ __align__(16) u16 STl[16*136];
    __shared__ float bvv[2][64], esc[64];
    const int tid = threadIdx.x, lane = tid&63, wave = tid>>6;
    const int lr = lane&15, lg = lane>>4;
    const int blk = blockIdx.x;
    const int bh = blk & 31, vs = blk >> 5;       // vs 0..7
    const int b = bh>>4, h = bh&15, v0 = vs*16;
    const u16* qgb = mixed + (size_t)b*T_SEQ*CONV_CH + h*128;
    const u16* kgb = qgb + KD;

    float sreg[2][4];
    #pragma unroll
    for (int i=0;i<2;i++)
        #pragma unroll
        for (int r=0;r<4;r++) sreg[i][r] = 0.f;
    for (int i=tid; i<16*136; i+=256){ STh[i]=0; STl[i]=0; }

    auto STAGE = [&](int ci2, int bf){
        const size_t ch = (size_t)(bh*64 + ci2);
        #pragma unroll
        for (int pass=0; pass<4; pass++){
            gl_lds16(Wcg + ch*8192 + pass*2048 + tid*8, &WcS[bf][pass*2048 + tid*8]);
            int row = pass*16 + (tid>>4), co = (tid&15)*8;
            gl_lds16(kgb + ((size_t)(ci2*64) + row)*CONV_CH + co, &Ks[bf][row*128 + co]);
            gl_lds16(qgb + ((size_t)(ci2*64) + row)*CONV_CH + co, &Qs[bf][row*128 + co]);
        }
    };

    STAGE(0, 0);
    if (tid < 128){
        int row = tid>>1, c8 = (tid&1)*8;
        *(uint4*)&UcS[0][row*16 + c8] = *(const uint4*)(Ucg + (size_t)(bh*64)*8192 + (size_t)row*128 + v0 + c8);
    }
    if (tid<64) bvv[0][tid] = barr[(size_t)(bh*64)*64 + tid];
    __syncthreads();

    for (int ci=0; ci<64; ci++){
        const int cur = ci&1, nxt = cur^1;
        const size_t chunk = (size_t)(bh*64 + ci);
        const size_t rowbase = (size_t)b*T_SEQ + ci*64;
        uint4 ucv = {0,0,0,0}; float bvn = 0.f;
        const bool havenext = (ci+1 < 64);
        if (havenext){
            STAGE(ci+1, nxt);
            if (tid < 128)
                ucv = *(const uint4*)(Ucg + (chunk+1)*8192 + (size_t)(tid>>1)*128 + v0 + (tid&1)*8);
            if (tid<64) bvn = barr[(chunk+1)*64 + tid];
        }
        if (tid<64) esc[tid] = __expf(bvv[cur][63] - bvv[cur][tid]);
        // Delta = Uc - Wc@S0 -> DT [v][t]  (1 tile per wave: tm=wave)
        {
            const int tm = wave;
            f32x4 acc = {};
            #pragma unroll
            for (int kk=0;kk<4;kk++){
                bf16x8 af = frag(WcS[cur], tm*16+lr, 128, kk*32+lg*8);
                acc = __builtin_amdgcn_mfma_f32_16x16x32_bf16(af, frag(STh, lr, 136, kk*32+lg*8), acc, 0,0,0);
                acc = __builtin_amdgcn_mfma_f32_16x16x32_bf16(af, frag(STl, lr, 136, kk*32+lg*8), acc, 0,0,0);
            }
            #pragma unroll
            for (int r=0;r<4;r++){
                int t = tm*16+lg*4+r;
                DT[lr*72 + t] = f2bf(bf2f(UcS[cur][t*16+lr]) - acc[r]);
            }
        }
        // o1 = e^{b_t} * (Q @ S0)  (1 tile per wave), f32 out
        {
            const int tm = wave;
            f32x4 acc = {};
            #pragma unroll
            for (int kk=0;kk<4;kk++){
                bf16x8 af = frag(Qs[cur], tm*16+lr, 128, kk*32+lg*8);
                acc = __builtin_amdgcn_mfma_f32_16x16x32_bf16(af, frag(STh, lr, 136, kk*32+lg*8), acc, 0,0,0);
                acc = __builtin_amdgcn_mfma_f32_16x16x32_bf16(af, frag(STl, lr, 136, kk*32+lg*8), acc, 0,0,0);
            }
            #pragma unroll
            for (int r=0;r<4;r++){
                int t = tm*16+lg*4+r;
                o1g[((rowbase + t)*NH + h)*DKH + v0 + lr] = acc[r]*__expf(bvv[cur][t]);
            }
        }
        __syncthreads();
        // KpT[k][t] = K[t][k]*esc[t]  (u32-packed writes)
        for (int i=tid; i<4096; i+=256){
            int k = i & 127, t = (i >> 7) * 2;
            u32 pack = (u32)f2bf(bf2f(Ks[cur][t*128 + k]) * esc[t])
                     | ((u32)f2bf(bf2f(Ks[cur][(t+1)*128 + k]) * esc[t+1]) << 16);
            *(u32*)&KpT[(size_t)k*72 + t] = pack;
        }
        if (tid < 128){
            int vv = tid>>3, c = (tid&7)*8;
            *(uint4*)(DTg + chunk*8192 + (size_t)(v0+vv)*64 + c) = *(const uint4*)&DT[vv*72 + c];
        }
        if (havenext){
            if (tid < 128){
                int row = tid>>1, c8 = (tid&1)*8;
                *(uint4*)&UcS[nxt][row*16 + c8] = ucv;
            }
            if (tid<64) bvv[nxt][tid] = bvn;
        }
        __syncthreads();
        // S = e^{bC}*S + KpT @ DT^T   (2 tiles per wave)
        float lamC = __expf(bvv[cur][63]);
        #pragma unroll
        for (int i=0;i<2;i++){
            const int tm = wave*2 + i;
            f32x4 acc;
            #pragma unroll
            for (int r=0;r<4;r++) acc[r] = lamC * sreg[i][r];
            #pragma unroll
            for (int kk=0;kk<2;kk++)
                acc = __builtin_amdgcn_mfma_f32_16x16x32_bf16(
                    frag(KpT, tm*16+lr, 72, kk*32+lg*8),
                    frag(DT,  lr, 72, kk*32+lg*8), acc, 0,0,0);
            #pragma unroll
            for (int r=0;r<4;r++){
                int k = tm*16+lg*4+r;
                sreg[i][r] = acc[r];
                u16 hi = f2bf(acc[r]);
                STh[lr*136 + k] = hi;
                STl[lr*136 + k] = f2bf(acc[r] - bf2f(hi));
            }
        }
        __syncthreads();
    }
}

// ---------- o = o1 + QKmask @ Delta ; fused gate+RMSNorm -> x written in-place into zbuf ----------
__global__ __launch_bounds__(256) void k_out(const u16* __restrict__ mixed,
        const float* __restrict__ barr, const float* __restrict__ o1g,
        const u16* __restrict__ DTg, u16* __restrict__ zio,
        const float* __restrict__ norm_w){
    __shared__ __align__(16) u16 Qs[64*128];
    __shared__ __align__(16) u16 Ks[64*128];
    __shared__ __align__(16) u16 DTs[128*64];
    __shared__ __align__(16) u16 QKm[64*72];
    __shared__ float bvv[64];
    __shared__ float nw[128];
    const int tid = threadIdx.x, lane = tid&63, wave = tid>>6;
    const int lr = lane&15, lg = lane>>4;
    const int chunk = blockIdx.x;
    const int ci = chunk&63, bh = chunk>>6, b = bh>>4, h = bh&15;
    const size_t rowbase = (size_t)b*T_SEQ + ci*64;
    const u16* qg = mixed + rowbase*CONV_CH + h*128;
    const u16* kg = qg + KD;
    #pragma unroll
    for (int pass=0; pass<4; pass++){
        int row = pass*16 + (tid>>4), co = (tid&15)*8;
        gl_lds16(qg + (size_t)row*CONV_CH + co, Qs + row*128 + co);
        gl_lds16(kg + (size_t)row*CONV_CH + co, Ks + row*128 + co);
        gl_lds16(DTg + (size_t)chunk*8192 + pass*2048 + tid*8, DTs + pass*2048 + tid*8);
    }
    if (tid<64) bvv[tid] = barr[(size_t)chunk*64 + tid];
    if (tid<128) nw[tid] = norm_w[tid];
    __syncthreads();
    {
        f32x4 acc[4];
        #pragma unroll
        for (int tn=0; tn<4; tn++){
            f32x4 a = {};
            #pragma unroll
            for (int kk=0;kk<4;kk++)
                a = __builtin_amdgcn_mfma_f32_16x16x32_bf16(
                    frag(Qs, wave*16+lr, 128, kk*32+lg*8),
                    frag(Ks, tn*16+lr, 128, kk*32+lg*8), a, 0,0,0);
            acc[tn] = a;
        }
        #pragma unroll
        for (int tn=0;tn<4;tn++)
            #pragma unroll
            for (int r=0;r<4;r++){
                int t = wave*16+lg*4+r, s = tn*16+lr;
                float val = (t>=s) ? acc[tn][r]*__expf(bvv[t]-bvv[s]) : 0.f;
                QKm[t*72+s] = f2bf(val);
            }
    }
    __syncthreads();
    f32x4 acc[8] = {};
    #pragma unroll
    for (int kk=0;kk<2;kk++){
        bf16x8 af = frag(QKm, wave*16+lr, 72, kk*32+lg*8);
        #pragma unroll
        for (int tn=0;tn<8;tn++)
            acc[tn] = __builtin_amdgcn_mfma_f32_16x16x32_bf16(af, frag(DTs, tn*16+lr, 64, kk*32+lg*8), acc[tn], 0,0,0);
    }
    // fused epilogue: x = RMSNorm((o1 + QKm@Delta) * silu(z)) * norm_w, overwrite z in place.
    float xv[8][4];
    float ss[4] = {0.f,0.f,0.f,0.f};
    #pragma unroll
    for (int tn=0;tn<8;tn++)
        #pragma unroll
        for (int r=0;r<4;r++){
            int t = wave*16+lg*4+r, v = tn*16+lr;
            size_t bt = rowbase + t;
            float ov = o1g[(bt*NH + h)*DKH + v] + acc[tn][r];
            float z  = bf2f(zio[bt*VD + h*DKH + v]);
            float xx = ov * (z/(1.f+__expf(-z)));
            xv[tn][r] = xx;
            ss[r] = fmaf(xx, xx, ss[r]);
        }
    #pragma unroll
    for (int m=1;m<16;m<<=1)
        #pragma unroll
        for (int r=0;r<4;r++) ss[r] += __shfl_xor(ss[r], m, 64);
    float sc[4];
    #pragma unroll
    for (int r=0;r<4;r++) sc[r] = rsqrtf(ss[r]*(1.f/128.f) + 1e-6f);
    #pragma unroll
    for (int tn=0;tn<8;tn++)
        #pragma unroll
        for (int r=0;r<4;r++){
            int t = wave*16+lg*4+r, v = tn*16+lr;
            zio[(rowbase + t)*VD + h*DKH + v] = f2bf(xv[tn][r]*sc[r]*nw[v]);
        }
}

extern "C" void kernel_launch(void* const* d_in, const int* in_sizes, int n_in,
                              void* d_out, int out_size, void* d_ws, size_t ws_size,
                              hipStream_t stream){
    (void)in_sizes; (void)n_in; (void)out_size; (void)ws_size;
    const float* hidden = (const float*)d_in[0];
    const float* W_qkvz = (const float*)d_in[1];
    const float* W_ba   = (const float*)d_in[2];
    const float* conv_w = (const float*)d_in[3];
    const float* conv_b = (const float*)d_in[4];
    const float* dt_bias= (const float*)d_in[5];
    const float* A_log  = (const float*)d_in[6];
    const float* norm_w = (const float*)d_in[7];
    const float* W_out  = (const float*)d_in[8];
    float* out = (float*)d_out;

    char* ws = (char*)d_ws;
    size_t off = 0;
    auto alloc = [&](size_t bytes)->char*{ char* p = ws + off; off += (bytes + 255) & ~(size_t)255; return p; };
    // Pool A (100.66 MB): h_bf|WqT -> Wcg|Ucg|DTg
    char* poolA = alloc(100663296);
    u16*   h_bf = (u16*)poolA;
    u16*   WqT  = (u16*)(poolA + 50331648);
    u16*   Wcg  = (u16*)poolA;
    u16*   Ucg  = (u16*)(poolA + 33554432);
    u16*   DTg  = (u16*)(poolA + 67108864);
    // Pool B (100.66 MB): qkv_lin -> o1g|barr
    char* poolB = alloc(100663296);
    u16*   qkv_lin = (u16*)poolB;
    float* o1g  = (float*)poolB;
    float* barr = (float*)(poolB + 67108864);
    u16*   WoT  = (u16*)  alloc((size_t)HID*VD*2);        // 12.6 MB
    u16*   zbuf = (u16*)  alloc((size_t)MROWS*VD*2);      // 33.55 MB (z -> x in place)
    u16*   mixed= (u16*)  alloc((size_t)MROWS*CONV_CH*2); // 100.66 MB
    float2* be_b= (float2*)alloc((size_t)MROWS*NH*8);     // 1.05 MB
    // total 349.2 MB == proven footprint

    k_cast<<<2048,256,0,stream>>>(hidden, h_bf, MROWS*HID/4);
    k_transpose_cast<<<(HID/32)*(N_QKVZ/32),256,0,stream>>>(W_qkvz, WqT, HID, N_QKVZ);
    k_transpose_cast<<<(VD/32)*(HID/32),256,0,stream>>>(W_out, WoT, VD, HID);
    k_gemm_bt<true><<<(MROWS/128)*(N_QKVZ/128),256,0,stream>>>(h_bf, WqT, qkv_lin, zbuf,
                         MROWS, N_QKVZ, HID, CONV_CH, CONV_CH, VD);
    k_ba<<<MROWS/8,256,0,stream>>>(hidden, W_ba, dt_bias, A_log, be_b);
    k_conv_silu<<<(MROWS/8)*24,256,0,stream>>>(qkv_lin, conv_w, conv_b, mixed);
    k_prep<<<2048,512,0,stream>>>(mixed, be_b, Wcg, Ucg, barr);
    k_seq<<<256,256,0,stream>>>(mixed, Wcg, Ucg, barr, o1g, DTg);
    k_out<<<2048,256,0,stream>>>(mixed, barr, o1g, DTg, zbuf, norm_w);
    k_gemm_bt<false><<<(MROWS/128)*(HID/128),256,0,stream>>>(zbuf, WoT, out, nullptr,
                         MROWS, HID, VD, 1<<30, HID, 0);
}